// Round 12
// baseline (576.312 us; speedup 1.0000x reference)
//
#include <hip/hip_runtime.h>
#include <hip/hip_bf16.h>
#include <cstdint>
#include <cstddef>

#define NEG_SLOPE 0.2f

typedef float f4v __attribute__((ext_vector_type(4)));
typedef float f8v __attribute__((ext_vector_type(8)));
typedef _Float16 h8v __attribute__((ext_vector_type(8)));
typedef short short8 __attribute__((ext_vector_type(8)));
typedef float f32x4 __attribute__((ext_vector_type(4)));

// Explicit round-to-nearest-even fp32 -> bf16 (integer form; r12 evidence:
// __float2bfloat16 truncates on this ROCm -> biased residual -> e-3 scatter).
__device__ __forceinline__ short rne_bf16(float v) {
  unsigned u = __builtin_bit_cast(unsigned, v);
  u += 0x7FFFu + ((u >> 16) & 1u);
  return (short)(u >> 16);
}
__device__ __forceinline__ float bf16_to_f(short h) {
  unsigned u = ((unsigned)(unsigned short)h) << 16;
  return __builtin_bit_cast(float, u);
}
// fp32 -> 3x bf16, RNE at each level. Residual <= 2^-27|v|, unbiased.
// R6 LESSON: double-split (2 planes / 3 MFMA terms) measured absmax 4.55e-3
// vs threshold 4.34e-3 — the GEMM split must stay TRIPLE.
// R9 LESSON: L/R-fused GEMM regressed +25 us (doubled per-wave W traffic AND
// acc regs). R12 is the opposite: halve rows/wave -> acc 64->32 regs.
// R11: xl buffer is fp16; xr/res/y stay fp32.
__device__ __forceinline__ void cvt3(float v, short& h, short& m, short& l) {
  h = rne_bf16(v);
  float r1 = v - bf16_to_f(h);
  m = rne_bf16(r1);
  float r2 = r1 - bf16_to_f(m);
  l = rne_bf16(r2);
}

// ---------- CSR build ----------
// deg[] holds EDGE-ONLY in-degree (self-loop +1 folded into consumers);
// initialized by hipMemsetAsync(0) instead of a fill kernel.

__global__ __launch_bounds__(256) void degree_count_kernel(
    const int* __restrict__ ei, int E, int* __restrict__ deg) {
  int e = blockIdx.x * 256 + threadIdx.x;
  if (e < E) atomicAdd(&deg[ei[E + e]], 1);
}

__global__ __launch_bounds__(1024) void scan1_kernel(
    const int* __restrict__ deg, int n, int* __restrict__ incl,
    int* __restrict__ blocksums) {
  __shared__ int sm[1024];
  int t = threadIdx.x;
  int i = blockIdx.x * 1024 + t;
  sm[t] = (i < n) ? (deg[i] + 1) : 0;  // +1: self loop
  __syncthreads();
  #pragma unroll
  for (int o = 1; o < 1024; o <<= 1) {
    int a = (t >= o) ? sm[t - o] : 0;
    __syncthreads();
    sm[t] += a;
    __syncthreads();
  }
  if (i < n) incl[i] = sm[t];
  if (t == 1023) blocksums[blockIdx.x] = sm[t];
}

// scan3 with scan2 folded in: every block locally prefix-sums the (<=1024)
// block sums (NB ~ 98 -> negligible), then writes exclusive row starts.
__global__ __launch_bounds__(1024) void scan23_kernel(
    const int* __restrict__ incl, const int* __restrict__ deg,
    const int* __restrict__ bs, int nb, int n, int* __restrict__ rowcur) {
  int i = blockIdx.x * 1024 + threadIdx.x;
  if (i >= n) return;
  int off = 0;
  for (int j = 0; j < (int)blockIdx.x; j++) off += bs[j];  // nb<=98, L2-hot
  rowcur[i] = incl[i] - (deg[i] + 1) + off;
}

__global__ __launch_bounds__(256) void scatter_kernel(
    const int* __restrict__ ei, int E, int ET, int* __restrict__ rowcur,
    int* __restrict__ csr_src) {
  int e = blockIdx.x * 256 + threadIdx.x;
  if (e >= ET) return;
  int s, d;
  if (e < E) { s = ei[e]; d = ei[E + e]; }
  else       { s = e - E; d = s; }
  int pos = atomicAdd(&rowcur[d], 1);
  csr_src[pos] = s;
}

// ---------- W -> MFMA B-fragment layout (triple bf16 planes) ----------
struct PrepArgs {
  const float* w[8];
  short* o[8];
  int fout[8];
  int cum[9];
};

__global__ __launch_bounds__(256) void prep_w_kernel(PrepArgs pa) {
  int i = blockIdx.x * 256 + threadIdx.x;
  if (i >= pa.cum[8]) return;
  int s = 0;
  while (i >= pa.cum[s + 1]) s++;
  int li = i - pa.cum[s];
  int FOUT = pa.fout[s];
  int NT = FOUT >> 4;
  int sz = pa.cum[s + 1] - pa.cum[s];
  int c = li / (NT * 512);
  int r1 = li % (NT * 512);
  int t = r1 >> 9;
  int e = r1 & 511;
  int lane = e >> 3, j = e & 7;
  int k = c * 32 + (lane >> 4) * 8 + j;
  int n = t * 16 + (lane & 15);
  float v = pa.w[s][k * FOUT + n];
  short h, m, l;
  cvt3(v, h, m, l);
  pa.o[s][li] = h;
  pa.o[s][li + sz] = m;
  pa.o[s][li + 2 * sz] = l;
}

// 6-term triple-split MFMA accumulate for one tile
#define MFMA6(ah, am, al, bh, bm, bl, acc)                                   \
  acc = __builtin_amdgcn_mfma_f32_16x16x32_bf16(ah, bh, acc, 0, 0, 0);      \
  acc = __builtin_amdgcn_mfma_f32_16x16x32_bf16(ah, bm, acc, 0, 0, 0);      \
  acc = __builtin_amdgcn_mfma_f32_16x16x32_bf16(am, bh, acc, 0, 0, 0);      \
  acc = __builtin_amdgcn_mfma_f32_16x16x32_bf16(ah, bl, acc, 0, 0, 0);      \
  acc = __builtin_amdgcn_mfma_f32_16x16x32_bf16(am, bm, acc, 0, 0, 0);      \
  acc = __builtin_amdgcn_mfma_f32_16x16x32_bf16(al, bh, acc, 0, 0, 0);

// ---------- layer-0 GEMM: fused LN64, 16 rows/wave, y-split L/R ------------
// R12: 32 -> 16 rows/wave. R11 PMC on the lr twin: MfmaUtil 17%, VALU 15%,
// HBM 19%, Occupancy 26% — latency-bound at 3 waves/SIMD (84 arch VGPR + 64
// acc AGPR ~ 148 regs). Halving rows halves acc (32 regs) -> ~116 total ->
// 4 waves/SIMD under launch_bounds(256,4), 2x blocks. Per-output op sequence
// bit-identical (same cvt3 inputs, same MFMA order).
__global__ __launch_bounds__(256, 4) void mfma_gemm_ln_kernel(
    const float* __restrict__ X, const float* __restrict__ lng,
    const float* __restrict__ lnb, const short* __restrict__ WfL,
    const short* __restrict__ WfR, _Float16* __restrict__ YL,
    float* __restrict__ YR, int nrows) {
  constexpr int NT = 8, TOT = 2 * NT * 512;
  const short* Wf = blockIdx.y ? WfR : WfL;
  const int isL = (blockIdx.y == 0);
  const int wave = threadIdx.x >> 6, lane = threadIdx.x & 63;
  const int quad = lane >> 4, ln16 = lane & 15;
  const int rb = blockIdx.x * 64 + wave * 16;
  int r0 = rb + ln16;
  int rA0 = r0 < nrows ? r0 : nrows - 1;
  const float* xp0 = X + (size_t)rA0 * 64 + quad * 8;

  float av[16];
  *(float4*)&av[0]  = *(const float4*)(xp0);
  *(float4*)&av[4]  = *(const float4*)(xp0 + 4);
  *(float4*)&av[8]  = *(const float4*)(xp0 + 32);
  *(float4*)&av[12] = *(const float4*)(xp0 + 36);

  float s0 = 0.f, q0 = 0.f;
  #pragma unroll
  for (int j = 0; j < 16; j++) {
    s0 += av[j]; q0 += av[j] * av[j];
  }
  s0 += __shfl_xor(s0, 16); s0 += __shfl_xor(s0, 32);
  q0 += __shfl_xor(q0, 16); q0 += __shfl_xor(q0, 32);
  float mean0 = s0 * (1.f / 64.f);
  float rstd0 = rsqrtf(q0 * (1.f / 64.f) - mean0 * mean0 + 1e-5f);

  f32x4 acc[NT];
  #pragma unroll
  for (int t = 0; t < NT; t++) acc[t] = (f32x4){0.f, 0.f, 0.f, 0.f};

  #pragma unroll
  for (int c = 0; c < 2; c++) {
    float4 gv0 = *(const float4*)&lng[quad * 8 + c * 32];
    float4 gv1 = *(const float4*)&lng[quad * 8 + c * 32 + 4];
    float4 bv0 = *(const float4*)&lnb[quad * 8 + c * 32];
    float4 bv1 = *(const float4*)&lnb[quad * 8 + c * 32 + 4];
    float gg[8] = {gv0.x, gv0.y, gv0.z, gv0.w, gv1.x, gv1.y, gv1.z, gv1.w};
    float bb[8] = {bv0.x, bv0.y, bv0.z, bv0.w, bv1.x, bv1.y, bv1.z, bv1.w};
    short8 ah, am, al;
    #pragma unroll
    for (int j = 0; j < 8; j++) {
      float v0 = (av[c * 8 + j] - mean0) * rstd0 * gg[j] + bb[j];
      short h, m, l;
      cvt3(v0, h, m, l); ah[j] = h; am[j] = m; al[j] = l;
    }
    const short* wp = Wf + c * NT * 512 + lane * 8;
    #pragma unroll
    for (int t = 0; t < NT; t++) {
      short8 bh = *(const short8*)(wp + t * 512);
      short8 bm = *(const short8*)(wp + t * 512 + TOT);
      short8 bl = *(const short8*)(wp + t * 512 + 2 * TOT);
      MFMA6(ah, am, al, bh, bm, bl, acc[t]);
    }
  }

  const int rbase = rb + quad * 4;
  #pragma unroll
  for (int t = 0; t < NT; t++)
    #pragma unroll
    for (int r = 0; r < 4; r++) {
      int ra = rbase + r;
      if (ra < nrows) {
        if (isL) YL[(size_t)ra * 128 + t * 16 + ln16] = (_Float16)acc[t][r];
        else     YR[(size_t)ra * 128 + t * 16 + ln16] = acc[t][r];
      }
    }
}

// ---------- generic MFMA GEMM: FIN=128, 16 rows/wave, y-split L/R ----------
__global__ __launch_bounds__(256, 4) void mfma_gemm_lr_kernel(
    const float* __restrict__ X, const short* __restrict__ WfL,
    const short* __restrict__ WfR, _Float16* __restrict__ YL,
    float* __restrict__ YR, int nrows) {
  constexpr int NC = 4, NT = 8, TOT = NC * NT * 512;
  const short* Wf = blockIdx.y ? WfR : WfL;
  const int isL = (blockIdx.y == 0);
  const int wave = threadIdx.x >> 6, lane = threadIdx.x & 63;
  const int quad = lane >> 4, ln16 = lane & 15;
  const int rb = blockIdx.x * 64 + wave * 16;
  int r0 = rb + ln16;
  int rA0 = r0 < nrows ? r0 : nrows - 1;
  const float* xp0 = X + (size_t)rA0 * 128 + quad * 8;

  f32x4 acc[NT];
  #pragma unroll
  for (int t = 0; t < NT; t++) acc[t] = (f32x4){0.f, 0.f, 0.f, 0.f};

  #pragma unroll
  for (int c = 0; c < NC; c++) {
    float4 x00 = *(const float4*)(xp0 + c * 32);
    float4 x01 = *(const float4*)(xp0 + c * 32 + 4);
    float a0[8] = {x00.x, x00.y, x00.z, x00.w, x01.x, x01.y, x01.z, x01.w};
    short8 ah, am, al;
    #pragma unroll
    for (int j = 0; j < 8; j++) {
      short h, m, l;
      cvt3(a0[j], h, m, l); ah[j] = h; am[j] = m; al[j] = l;
    }
    const short* wp = Wf + c * NT * 512 + lane * 8;
    #pragma unroll
    for (int t = 0; t < NT; t++) {
      short8 bh = *(const short8*)(wp + t * 512);
      short8 bm = *(const short8*)(wp + t * 512 + TOT);
      short8 bl = *(const short8*)(wp + t * 512 + 2 * TOT);
      MFMA6(ah, am, al, bh, bm, bl, acc[t]);
    }
  }

  const int rbase = rb + quad * 4;
  #pragma unroll
  for (int t = 0; t < NT; t++)
    #pragma unroll
    for (int r = 0; r < 4; r++) {
      int ra = rbase + r;
      if (ra < nrows) {
        if (isL) YL[(size_t)ra * 128 + t * 16 + ln16] = (_Float16)acc[t][r];
        else     YR[(size_t)ra * 128 + t * 16 + ln16] = acc[t][r];
      }
    }
}

// ---------- head GEMMs fused with final dots: out[row,0..1] in one block ---
__global__ __launch_bounds__(256, 2) void mfma_head_lr_kernel(
    const float* __restrict__ X, const short* __restrict__ Wf1,
    const float* __restrict__ b1a, const float* __restrict__ w2a,
    const float* __restrict__ b2a, const short* __restrict__ Wf2,
    const float* __restrict__ b1b, const float* __restrict__ w2b,
    const float* __restrict__ b2b, float* __restrict__ out, int nrows) {
  constexpr int NC = 4, NT = 4, TOT = NC * NT * 512;
  const int wave = threadIdx.x >> 6, lane = threadIdx.x & 63;
  const int quad = lane >> 4, ln16 = lane & 15;
  int rowA = blockIdx.x * 64 + wave * 16 + ln16;
  int rA = rowA < nrows ? rowA : nrows - 1;
  const float* xp = X + (size_t)rA * 128 + quad * 8;

  f32x4 accL[NT], accR[NT];
  #pragma unroll
  for (int t = 0; t < NT; t++) {
    accL[t] = (f32x4){0.f, 0.f, 0.f, 0.f};
    accR[t] = (f32x4){0.f, 0.f, 0.f, 0.f};
  }

  #pragma unroll
  for (int c = 0; c < NC; c++) {
    float4 a0 = *(const float4*)(xp + c * 32);
    float4 a1 = *(const float4*)(xp + c * 32 + 4);
    float av[8] = {a0.x, a0.y, a0.z, a0.w, a1.x, a1.y, a1.z, a1.w};
    short8 ah, am, al;
    #pragma unroll
    for (int j = 0; j < 8; j++) {
      short h, m, l;
      cvt3(av[j], h, m, l);
      ah[j] = h; am[j] = m; al[j] = l;
    }
    const short* wpL = Wf1 + c * NT * 512 + lane * 8;
    const short* wpR = Wf2 + c * NT * 512 + lane * 8;
    #pragma unroll
    for (int t = 0; t < NT; t++) {
      short8 bh = *(const short8*)(wpL + t * 512);
      short8 bm = *(const short8*)(wpL + t * 512 + TOT);
      short8 bl = *(const short8*)(wpL + t * 512 + 2 * TOT);
      MFMA6(ah, am, al, bh, bm, bl, accL[t]);
      short8 ch = *(const short8*)(wpR + t * 512);
      short8 cm = *(const short8*)(wpR + t * 512 + TOT);
      short8 cl = *(const short8*)(wpR + t * 512 + 2 * TOT);
      MFMA6(ah, am, al, ch, cm, cl, accR[t]);
    }
  }

  float prA[4] = {0.f, 0.f, 0.f, 0.f};
  float prB[4] = {0.f, 0.f, 0.f, 0.f};
  #pragma unroll
  for (int t = 0; t < NT; t++) {
    float bvA = b1a[t * 16 + ln16], wvA = w2a[t * 16 + ln16];
    float bvB = b1b[t * 16 + ln16], wvB = w2b[t * 16 + ln16];
    #pragma unroll
    for (int r = 0; r < 4; r++) {
      prA[r] += fmaxf(accL[t][r] + bvA, 0.f) * wvA;
      prB[r] += fmaxf(accR[t][r] + bvB, 0.f) * wvB;
    }
  }
  #pragma unroll
  for (int o = 1; o < 16; o <<= 1)
    #pragma unroll
    for (int r = 0; r < 4; r++) {
      prA[r] += __shfl_xor(prA[r], o);
      prB[r] += __shfl_xor(prB[r], o);
    }
  if (ln16 == 0) {
    const float bb2a = b2a[0], bb2b = b2b[0];
    const int rbase = blockIdx.x * 64 + wave * 16 + quad * 4;
    #pragma unroll
    for (int r = 0; r < 4; r++) {
      int rr = rbase + r;
      if (rr < nrows) {
        out[(size_t)rr * 2 + 0] = prA[r] + bb2a;
        out[(size_t)rr * 2 + 1] = prB[r] + bb2b;
      }
    }
  }
}

// ---------- fused GAT layer -------------------------------------------------
// R7 structure: two rows per 64-lane wave, 2 edge-streams x 16 channel-lanes
// per row, 1-wave blocks, per-lane scalar index loads, depth-2 gather
// pipeline. R10: no NT hints (L3 retention, −12 us). R11: xl is fp16 (−62 us;
// halves gather payload). FROZEN.
template <int H>
__global__ __launch_bounds__(64) void gat_fused_kernel(
    const _Float16* __restrict__ xl, const float* __restrict__ xr,
    const int* __restrict__ csr_src, const int* __restrict__ row_end,
    const int* __restrict__ deg, const float* __restrict__ att,
    const float* __restrict__ res, const float* __restrict__ g,
    const float* __restrict__ b, float* __restrict__ y, int n,
    float resScale, int doRelu) {
  int l = threadIdx.x & 63;
  int rh = l >> 5;          // row-half within wave (0/1)
  int st = (l >> 4) & 1;    // edge-stream within row (0/1)
  int ln = l & 15;          // channel-lane within stream
  int row = blockIdx.x * 2 + rh;
  int rowC = row < n ? row : n - 1;  // clamp (stores guarded)
  int cb = ln * 32;   // byte offset of lane's 8-channel chunk (fp32 arrays)
  int cbh = ln * 16;  // byte offset in fp16 xl rows (256B/row)
  int end = row_end[rowC];
  int dg = deg[rowC] + 1;  // + self loop
  int start = end - dg;
  int cnt = (dg - st + 1) >> 1;  // edges for this stream (dg >= 1 always)

  const char* xrb = (const char*)xr + (size_t)rowC * 512 + cb;
  f4v xr0 = *(const f4v*)xrb;
  f4v xr1 = *(const f4v*)(xrb + 16);
  f4v av0 = *(const f4v*)((const char*)att + cb);
  f4v av1 = *(const f4v*)((const char*)att + cb + 16);

  float s = 0.f;
  float ac[8] = {0.f, 0.f, 0.f, 0.f, 0.f, 0.f, 0.f, 0.f};

  int idx = start + st;
  h8v pa = (h8v)0, pb = (h8v)0;  // depth-2 pipeline, fp16 payload
  if (cnt > 0)
    pa = *(const h8v*)((const char*)xl + (size_t)csr_src[idx] * 256 + cbh);
  if (cnt > 1)
    pb = *(const h8v*)((const char*)xl + (size_t)csr_src[idx + 2] * 256 + cbh);
  for (int i = 0; i < cnt; i++) {
    f8v xv = __builtin_convertvector(pa, f8v);
    pa = pb;
    if (i + 2 < cnt)
      pb = *(const h8v*)((const char*)xl + (size_t)csr_src[idx + 4] * 256 + cbh);
    idx += 2;
    float p0;
    {
      float t0 = xv[0] + xr0.x, t1 = xv[1] + xr0.y;
      float t2 = xv[2] + xr0.z, t3 = xv[3] + xr0.w;
      float t4 = xv[4] + xr1.x, t5 = xv[5] + xr1.y;
      float t6 = xv[6] + xr1.z, t7 = xv[7] + xr1.w;
      float v0 = fmaxf(t0, NEG_SLOPE * t0), v1 = fmaxf(t1, NEG_SLOPE * t1);
      float v2 = fmaxf(t2, NEG_SLOPE * t2), v3 = fmaxf(t3, NEG_SLOPE * t3);
      float v4 = fmaxf(t4, NEG_SLOPE * t4), v5 = fmaxf(t5, NEG_SLOPE * t5);
      float v6 = fmaxf(t6, NEG_SLOPE * t6), v7 = fmaxf(t7, NEG_SLOPE * t7);
      p0 = v0 * av0.x + v1 * av0.y + v2 * av0.z + v3 * av0.w +
           v4 * av1.x + v5 * av1.y + v6 * av1.z + v7 * av1.w;
    }
    if constexpr (H == 1) {  // logit over 128 ch = 16 lanes (one stream)
      #pragma unroll
      for (int o = 1; o < 16; o <<= 1) p0 += __shfl_xor(p0, o);
    } else {                 // H=4: head = 32 ch = 4 lanes
      p0 += __shfl_xor(p0, 1);
      p0 += __shfl_xor(p0, 2);
    }
    float e = __expf(p0);
    s += e;
    ac[0] += e * xv[0]; ac[1] += e * xv[1];
    ac[2] += e * xv[2]; ac[3] += e * xv[3];
    ac[4] += e * xv[4]; ac[5] += e * xv[5];
    ac[6] += e * xv[6]; ac[7] += e * xv[7];
  }
  // combine the two stream partials — xor 16 stays within this row's 32 lanes
  s += __shfl_xor(s, 16);
  #pragma unroll
  for (int j = 0; j < 8; j++) ac[j] += __shfl_xor(ac[j], 16);

  float inv = 1.f / s;
  float ov[8];
  #pragma unroll
  for (int j = 0; j < 8; j++) ov[j] = ac[j] * inv;

  // LayerNorm over 128 (16 lanes of a stream cover all channels)
  float sum = 0.f, sq = 0.f;
  #pragma unroll
  for (int j = 0; j < 8; j++) { sum += ov[j]; sq += ov[j] * ov[j]; }
  #pragma unroll
  for (int o = 1; o < 16; o <<= 1) {
    sum += __shfl_xor(sum, o);
    sq += __shfl_xor(sq, o);
  }
  float mean = sum * (1.f / 128.f);
  float var = sq * (1.f / 128.f) - mean * mean;
  float rstd = rsqrtf(var + 1e-5f);

  f4v gv0 = *(const f4v*)((const char*)g + cb);
  f4v gv1 = *(const f4v*)((const char*)g + cb + 16);
  f4v bv0 = *(const f4v*)((const char*)b + cb);
  f4v bv1 = *(const f4v*)((const char*)b + cb + 16);
  float gg[8] = {gv0.x, gv0.y, gv0.z, gv0.w, gv1.x, gv1.y, gv1.z, gv1.w};
  float bb[8] = {bv0.x, bv0.y, bv0.z, bv0.w, bv1.x, bv1.y, bv1.z, bv1.w};
  float rv[8];
  #pragma unroll
  for (int j = 0; j < 8; j++) rv[j] = (ov[j] - mean) * rstd * gg[j] + bb[j];
  if (res) {
    const char* rb = (const char*)res + (size_t)rowC * 512 + cb;
    f4v r0 = *(const f4v*)rb;
    f4v r1 = *(const f4v*)(rb + 16);
    rv[0] += resScale * r0.x; rv[1] += resScale * r0.y;
    rv[2] += resScale * r0.z; rv[3] += resScale * r0.w;
    rv[4] += resScale * r1.x; rv[5] += resScale * r1.y;
    rv[6] += resScale * r1.z; rv[7] += resScale * r1.w;
  }
  if (doRelu) {
    #pragma unroll
    for (int j = 0; j < 8; j++) rv[j] = fmaxf(rv[j], 0.f);
  }
  if (st == 0 && row < n) {
    char* yb = (char*)y + (size_t)row * 512 + cb;
    f4v o0 = {rv[0], rv[1], rv[2], rv[3]};
    f4v o1 = {rv[4], rv[5], rv[6], rv[7]};
    *(f4v*)yb = o0;
    *(f4v*)(yb + 16) = o1;
  }
}

// ---------- launch ----------
extern "C" void kernel_launch(void* const* d_in, const int* in_sizes, int n_in,
                              void* d_out, int out_size, void* d_ws,
                              size_t ws_size, hipStream_t stream) {
  const float* x       = (const float*)d_in[0];
  const int*   ei      = (const int*)d_in[1];
  const float* ln_in_g = (const float*)d_in[2];
  const float* ln_in_b = (const float*)d_in[3];
  const float* w_l1    = (const float*)d_in[4];
  const float* w_r1    = (const float*)d_in[5];
  const float* att1    = (const float*)d_in[6];
  const float* ln1_g   = (const float*)d_in[7];
  const float* ln1_b   = (const float*)d_in[8];
  const float* w_l2    = (const float*)d_in[9];
  const float* w_r2    = (const float*)d_in[10];
  const float* att2    = (const float*)d_in[11];
  const float* ln2_g   = (const float*)d_in[12];
  const float* ln2_b   = (const float*)d_in[13];
  const float* w_l3    = (const float*)d_in[14];
  const float* w_r3    = (const float*)d_in[15];
  const float* att3    = (const float*)d_in[16];
  const float* ln3_g   = (const float*)d_in[17];
  const float* ln3_b   = (const float*)d_in[18];
  const float* rtt_w1  = (const float*)d_in[19];
  const float* rtt_b1  = (const float*)d_in[20];
  const float* rtt_w2  = (const float*)d_in[21];
  const float* rtt_b2  = (const float*)d_in[22];
  const float* ret_w1  = (const float*)d_in[23];
  const float* ret_b1  = (const float*)d_in[24];
  const float* ret_w2  = (const float*)d_in[25];
  const float* ret_b2  = (const float*)d_in[26];

  const int N = in_sizes[0] / 64;
  const int E = in_sizes[1] / 2;
  const int ET = E + N;
  const size_t NF = (size_t)N * 128;

  float* A = (float*)d_ws;            // node features h / residual (fp32)
  _Float16* B = (_Float16*)(A + NF);  // xl (fp16; region sized NF floats)
  float* C = (float*)(A + 2 * NF);    // xr (fp32)
  int* deg     = (int*)(C + NF);      // N (edge-only degree; +1 = self loop)
  int* rowcur  = deg + N;             // N (row_end after scatter)
  int* incl    = rowcur + N;          // N
  int* bsums   = incl + N;            // 1024
  int* csr_src = bsums + 1024;        // ET
  short* wf = (short*)(((uintptr_t)(csr_src + ET) + 63) & ~(uintptr_t)63);

  float* out = (float*)d_out;

  // segments: wl1, wr1, wl2, wr2, wl3, wr3, rtt_w1, ret_w1
  const int segsz[8] = {64 * 128, 64 * 128, 128 * 128, 128 * 128,
                        128 * 128, 128 * 128, 128 * 64, 128 * 64};
  PrepArgs pa;
  pa.w[0] = w_l1; pa.w[1] = w_r1; pa.w[2] = w_l2; pa.w[3] = w_r2;
  pa.w[4] = w_l3; pa.w[5] = w_r3; pa.w[6] = rtt_w1; pa.w[7] = ret_w1;
  pa.fout[0] = 128; pa.fout[1] = 128; pa.fout[2] = 128; pa.fout[3] = 128;
  pa.fout[4] = 128; pa.fout[5] = 128; pa.fout[6] = 64; pa.fout[7] = 64;
  int acc = 0;
  short* op = wf;
  for (int s = 0; s < 8; s++) {
    pa.cum[s] = acc;
    pa.o[s] = op;
    op += 3 * segsz[s];  // h + m + l planes
    acc += segsz[s];
  }
  pa.cum[8] = acc;

  const int mmBlocks   = (N + 63) / 64;    // head kernel + 16-row GEMMs
  const int gatBlocks  = (N + 1) / 2;      // gat: 2 rows per 1-wave block
  const int NB = (N + 1023) / 1024;
  dim3 lrGrid(mmBlocks, 2);

  // ---- W fragment prep ----
  prep_w_kernel<<<(acc + 255) / 256, 256, 0, stream>>>(pa);

  // ---- CSR build (by dst) ----
  hipMemsetAsync(deg, 0, (size_t)N * sizeof(int), stream);
  degree_count_kernel<<<(E + 255) / 256, 256, 0, stream>>>(ei, E, deg);
  scan1_kernel<<<NB, 1024, 0, stream>>>(deg, N, incl, bsums);
  scan23_kernel<<<NB, 1024, 0, stream>>>(incl, deg, bsums, NB, N, rowcur);
  scatter_kernel<<<(ET + 255) / 256, 256, 0, stream>>>(ei, E, ET, rowcur, csr_src);

  // ---- layer 0: fused LN64 + GEMM 64->128 (y-split L/R), 4 heads, relu ----
  mfma_gemm_ln_kernel<<<lrGrid, 256, 0, stream>>>(
      x, ln_in_g, ln_in_b, pa.o[0], pa.o[1], B, C, N);
  gat_fused_kernel<4><<<gatBlocks, 64, 0, stream>>>(
      B, C, csr_src, rowcur, deg, att1, nullptr, ln1_g, ln1_b, A, N, 0.f, 1);

  // ---- layer 1: 128 -> 128 (y-split L/R), 4 heads, residual 0.1, relu ----
  mfma_gemm_lr_kernel<<<lrGrid, 256, 0, stream>>>(A, pa.o[2], pa.o[3], B, C, N);
  gat_fused_kernel<4><<<gatBlocks, 64, 0, stream>>>(
      B, C, csr_src, rowcur, deg, att2, A, ln2_g, ln2_b, A, N, 0.1f, 1);

  // ---- layer 2: 128 -> 128 (y-split L/R), 1 head, residual 0.1, no relu ----
  mfma_gemm_lr_kernel<<<lrGrid, 256, 0, stream>>>(A, pa.o[4], pa.o[5], B, C, N);
  gat_fused_kernel<1><<<gatBlocks, 64, 0, stream>>>(
      B, C, csr_src, rowcur, deg, att3, A, ln3_g, ln3_b, A, N, 0.1f, 0);

  // ---- prediction heads: both GEMMs + relu + final dots in one dispatch ----
  mfma_head_lr_kernel<<<mmBlocks, 256, 0, stream>>>(
      A, pa.o[6], rtt_b1, rtt_w2, rtt_b2, pa.o[7], ret_b1, ret_w2, ret_b2,
      out, N);
}

// Round 13
// 533.350 us; speedup vs baseline: 1.0806x; 1.0806x over previous
//
#include <hip/hip_runtime.h>
#include <hip/hip_bf16.h>
#include <cstdint>
#include <cstddef>

#define NEG_SLOPE 0.2f

typedef float f4v __attribute__((ext_vector_type(4)));
typedef float f8v __attribute__((ext_vector_type(8)));
typedef _Float16 h8v __attribute__((ext_vector_type(8)));
typedef short short8 __attribute__((ext_vector_type(8)));
typedef float f32x4 __attribute__((ext_vector_type(4)));

// ---- GEMM numeric scheme (R13): DUAL-FP16 split, 3 MFMA terms/tile ----
// a = ah + al with ah=fp16RNE(a), al=fp16RNE(a-ah): residual <= 2^-22|a|
// (fp16 = 11 mantissa bits/plane). Dropped al*bl term <= 2^-22|ab|. Per
// GEMM output ~3e-6 absolute (<=6e-5 if low plane denormal-flushes) vs
// 2.6e-3 margin. R6 LESSON: the same 3-term scheme in BF16 (2^-16) FAILED
// at 4.55e-3 — plane precision, not term count, was the issue.
// R9 LESSON: L/R-fused GEMM regressed (2x W traffic + acc regs) — y-split
// stays. R11: xl fp16 (halved gather). R12: 16 rows/wave (occ 26->41%).
__device__ __forceinline__ void cvt2h(float v, _Float16& h, _Float16& l) {
  h = (_Float16)v;               // v_cvt_f16_f32, RNE in HW
  l = (_Float16)(v - (float)h);  // exact subtract, then RNE
}

// ---------- CSR build ----------
// deg[] holds EDGE-ONLY in-degree (self-loop +1 folded into consumers);
// initialized by hipMemsetAsync(0) instead of a fill kernel.

__global__ __launch_bounds__(256) void degree_count_kernel(
    const int* __restrict__ ei, int E, int* __restrict__ deg) {
  int e = blockIdx.x * 256 + threadIdx.x;
  if (e < E) atomicAdd(&deg[ei[E + e]], 1);
}

__global__ __launch_bounds__(1024) void scan1_kernel(
    const int* __restrict__ deg, int n, int* __restrict__ incl,
    int* __restrict__ blocksums) {
  __shared__ int sm[1024];
  int t = threadIdx.x;
  int i = blockIdx.x * 1024 + t;
  sm[t] = (i < n) ? (deg[i] + 1) : 0;  // +1: self loop
  __syncthreads();
  #pragma unroll
  for (int o = 1; o < 1024; o <<= 1) {
    int a = (t >= o) ? sm[t - o] : 0;
    __syncthreads();
    sm[t] += a;
    __syncthreads();
  }
  if (i < n) incl[i] = sm[t];
  if (t == 1023) blocksums[blockIdx.x] = sm[t];
}

// scan3 with scan2 folded in: every block locally prefix-sums the (<=1024)
// block sums (NB ~ 98 -> negligible), then writes exclusive row starts.
__global__ __launch_bounds__(1024) void scan23_kernel(
    const int* __restrict__ incl, const int* __restrict__ deg,
    const int* __restrict__ bs, int nb, int n, int* __restrict__ rowcur) {
  int i = blockIdx.x * 1024 + threadIdx.x;
  if (i >= n) return;
  int off = 0;
  for (int j = 0; j < (int)blockIdx.x; j++) off += bs[j];  // nb<=98, L2-hot
  rowcur[i] = incl[i] - (deg[i] + 1) + off;
}

__global__ __launch_bounds__(256) void scatter_kernel(
    const int* __restrict__ ei, int E, int ET, int* __restrict__ rowcur,
    int* __restrict__ csr_src) {
  int e = blockIdx.x * 256 + threadIdx.x;
  if (e >= ET) return;
  int s, d;
  if (e < E) { s = ei[e]; d = ei[E + e]; }
  else       { s = e - E; d = s; }
  int pos = atomicAdd(&rowcur[d], 1);
  csr_src[pos] = s;
}

// ---------- W -> MFMA B-fragment layout (dual fp16 planes) ----------
struct PrepArgs {
  const float* w[8];
  short* o[8];
  int fout[8];
  int cum[9];
};

__global__ __launch_bounds__(256) void prep_w_kernel(PrepArgs pa) {
  int i = blockIdx.x * 256 + threadIdx.x;
  if (i >= pa.cum[8]) return;
  int s = 0;
  while (i >= pa.cum[s + 1]) s++;
  int li = i - pa.cum[s];
  int FOUT = pa.fout[s];
  int NT = FOUT >> 4;
  int sz = pa.cum[s + 1] - pa.cum[s];
  int c = li / (NT * 512);
  int r1 = li % (NT * 512);
  int t = r1 >> 9;
  int e = r1 & 511;
  int lane = e >> 3, j = e & 7;
  int k = c * 32 + (lane >> 4) * 8 + j;
  int n = t * 16 + (lane & 15);
  float v = pa.w[s][k * FOUT + n];
  _Float16 h, l;
  cvt2h(v, h, l);
  pa.o[s][li] = __builtin_bit_cast(short, h);
  pa.o[s][li + sz] = __builtin_bit_cast(short, l);
}

// 3-term dual-fp16 MFMA accumulate for one tile (R13: was 6-term bf16)
#define MFMA3H(ah, al, bh, bl, acc)                                          \
  acc = __builtin_amdgcn_mfma_f32_16x16x32_f16(ah, bh, acc, 0, 0, 0);       \
  acc = __builtin_amdgcn_mfma_f32_16x16x32_f16(ah, bl, acc, 0, 0, 0);       \
  acc = __builtin_amdgcn_mfma_f32_16x16x32_f16(al, bh, acc, 0, 0, 0);

// ---------- layer-0 GEMM: fused LN64, 16 rows/wave, y-split L/R ------------
__global__ __launch_bounds__(256, 4) void mfma_gemm_ln_kernel(
    const float* __restrict__ X, const float* __restrict__ lng,
    const float* __restrict__ lnb, const short* __restrict__ WfL,
    const short* __restrict__ WfR, _Float16* __restrict__ YL,
    float* __restrict__ YR, int nrows) {
  constexpr int NT = 8, TOT = 2 * NT * 512;
  const short* Wf = blockIdx.y ? WfR : WfL;
  const int isL = (blockIdx.y == 0);
  const int wave = threadIdx.x >> 6, lane = threadIdx.x & 63;
  const int quad = lane >> 4, ln16 = lane & 15;
  const int rb = blockIdx.x * 64 + wave * 16;
  int r0 = rb + ln16;
  int rA0 = r0 < nrows ? r0 : nrows - 1;
  const float* xp0 = X + (size_t)rA0 * 64 + quad * 8;

  float av[16];
  *(float4*)&av[0]  = *(const float4*)(xp0);
  *(float4*)&av[4]  = *(const float4*)(xp0 + 4);
  *(float4*)&av[8]  = *(const float4*)(xp0 + 32);
  *(float4*)&av[12] = *(const float4*)(xp0 + 36);

  float s0 = 0.f, q0 = 0.f;
  #pragma unroll
  for (int j = 0; j < 16; j++) {
    s0 += av[j]; q0 += av[j] * av[j];
  }
  s0 += __shfl_xor(s0, 16); s0 += __shfl_xor(s0, 32);
  q0 += __shfl_xor(q0, 16); q0 += __shfl_xor(q0, 32);
  float mean0 = s0 * (1.f / 64.f);
  float rstd0 = rsqrtf(q0 * (1.f / 64.f) - mean0 * mean0 + 1e-5f);

  f32x4 acc[NT];
  #pragma unroll
  for (int t = 0; t < NT; t++) acc[t] = (f32x4){0.f, 0.f, 0.f, 0.f};

  #pragma unroll
  for (int c = 0; c < 2; c++) {
    float4 gv0 = *(const float4*)&lng[quad * 8 + c * 32];
    float4 gv1 = *(const float4*)&lng[quad * 8 + c * 32 + 4];
    float4 bv0 = *(const float4*)&lnb[quad * 8 + c * 32];
    float4 bv1 = *(const float4*)&lnb[quad * 8 + c * 32 + 4];
    float gg[8] = {gv0.x, gv0.y, gv0.z, gv0.w, gv1.x, gv1.y, gv1.z, gv1.w};
    float bb[8] = {bv0.x, bv0.y, bv0.z, bv0.w, bv1.x, bv1.y, bv1.z, bv1.w};
    h8v ah, al;
    #pragma unroll
    for (int j = 0; j < 8; j++) {
      float v0 = (av[c * 8 + j] - mean0) * rstd0 * gg[j] + bb[j];
      _Float16 h, l;
      cvt2h(v0, h, l); ah[j] = h; al[j] = l;
    }
    const short* wp = Wf + c * NT * 512 + lane * 8;
    #pragma unroll
    for (int t = 0; t < NT; t++) {
      h8v bh = *(const h8v*)(wp + t * 512);
      h8v bl = *(const h8v*)(wp + t * 512 + TOT);
      MFMA3H(ah, al, bh, bl, acc[t]);
    }
  }

  const int rbase = rb + quad * 4;
  #pragma unroll
  for (int t = 0; t < NT; t++)
    #pragma unroll
    for (int r = 0; r < 4; r++) {
      int ra = rbase + r;
      if (ra < nrows) {
        if (isL) YL[(size_t)ra * 128 + t * 16 + ln16] = (_Float16)acc[t][r];
        else     YR[(size_t)ra * 128 + t * 16 + ln16] = acc[t][r];
      }
    }
}

// ---------- generic MFMA GEMM: FIN=128, 16 rows/wave, y-split L/R ----------
__global__ __launch_bounds__(256, 4) void mfma_gemm_lr_kernel(
    const float* __restrict__ X, const short* __restrict__ WfL,
    const short* __restrict__ WfR, _Float16* __restrict__ YL,
    float* __restrict__ YR, int nrows) {
  constexpr int NC = 4, NT = 8, TOT = NC * NT * 512;
  const short* Wf = blockIdx.y ? WfR : WfL;
  const int isL = (blockIdx.y == 0);
  const int wave = threadIdx.x >> 6, lane = threadIdx.x & 63;
  const int quad = lane >> 4, ln16 = lane & 15;
  const int rb = blockIdx.x * 64 + wave * 16;
  int r0 = rb + ln16;
  int rA0 = r0 < nrows ? r0 : nrows - 1;
  const float* xp0 = X + (size_t)rA0 * 128 + quad * 8;

  f32x4 acc[NT];
  #pragma unroll
  for (int t = 0; t < NT; t++) acc[t] = (f32x4){0.f, 0.f, 0.f, 0.f};

  #pragma unroll
  for (int c = 0; c < NC; c++) {
    float4 x00 = *(const float4*)(xp0 + c * 32);
    float4 x01 = *(const float4*)(xp0 + c * 32 + 4);
    float a0[8] = {x00.x, x00.y, x00.z, x00.w, x01.x, x01.y, x01.z, x01.w};
    h8v ah, al;
    #pragma unroll
    for (int j = 0; j < 8; j++) {
      _Float16 h, l;
      cvt2h(a0[j], h, l); ah[j] = h; al[j] = l;
    }
    const short* wp = Wf + c * NT * 512 + lane * 8;
    #pragma unroll
    for (int t = 0; t < NT; t++) {
      h8v bh = *(const h8v*)(wp + t * 512);
      h8v bl = *(const h8v*)(wp + t * 512 + TOT);
      MFMA3H(ah, al, bh, bl, acc[t]);
    }
  }

  const int rbase = rb + quad * 4;
  #pragma unroll
  for (int t = 0; t < NT; t++)
    #pragma unroll
    for (int r = 0; r < 4; r++) {
      int ra = rbase + r;
      if (ra < nrows) {
        if (isL) YL[(size_t)ra * 128 + t * 16 + ln16] = (_Float16)acc[t][r];
        else     YR[(size_t)ra * 128 + t * 16 + ln16] = acc[t][r];
      }
    }
}

// ---------- head GEMMs fused with final dots: out[row,0..1] in one block ---
__global__ __launch_bounds__(256, 2) void mfma_head_lr_kernel(
    const float* __restrict__ X, const short* __restrict__ Wf1,
    const float* __restrict__ b1a, const float* __restrict__ w2a,
    const float* __restrict__ b2a, const short* __restrict__ Wf2,
    const float* __restrict__ b1b, const float* __restrict__ w2b,
    const float* __restrict__ b2b, float* __restrict__ out, int nrows) {
  constexpr int NC = 4, NT = 4, TOT = NC * NT * 512;
  const int wave = threadIdx.x >> 6, lane = threadIdx.x & 63;
  const int quad = lane >> 4, ln16 = lane & 15;
  int rowA = blockIdx.x * 64 + wave * 16 + ln16;
  int rA = rowA < nrows ? rowA : nrows - 1;
  const float* xp = X + (size_t)rA * 128 + quad * 8;

  f32x4 accL[NT], accR[NT];
  #pragma unroll
  for (int t = 0; t < NT; t++) {
    accL[t] = (f32x4){0.f, 0.f, 0.f, 0.f};
    accR[t] = (f32x4){0.f, 0.f, 0.f, 0.f};
  }

  #pragma unroll
  for (int c = 0; c < NC; c++) {
    float4 a0 = *(const float4*)(xp + c * 32);
    float4 a1 = *(const float4*)(xp + c * 32 + 4);
    float av[8] = {a0.x, a0.y, a0.z, a0.w, a1.x, a1.y, a1.z, a1.w};
    h8v ah, al;
    #pragma unroll
    for (int j = 0; j < 8; j++) {
      _Float16 h, l;
      cvt2h(av[j], h, l);
      ah[j] = h; al[j] = l;
    }
    const short* wpL = Wf1 + c * NT * 512 + lane * 8;
    const short* wpR = Wf2 + c * NT * 512 + lane * 8;
    #pragma unroll
    for (int t = 0; t < NT; t++) {
      h8v bh = *(const h8v*)(wpL + t * 512);
      h8v bl = *(const h8v*)(wpL + t * 512 + TOT);
      MFMA3H(ah, al, bh, bl, accL[t]);
      h8v ch = *(const h8v*)(wpR + t * 512);
      h8v cl = *(const h8v*)(wpR + t * 512 + TOT);
      MFMA3H(ah, al, ch, cl, accR[t]);
    }
  }

  float prA[4] = {0.f, 0.f, 0.f, 0.f};
  float prB[4] = {0.f, 0.f, 0.f, 0.f};
  #pragma unroll
  for (int t = 0; t < NT; t++) {
    float bvA = b1a[t * 16 + ln16], wvA = w2a[t * 16 + ln16];
    float bvB = b1b[t * 16 + ln16], wvB = w2b[t * 16 + ln16];
    #pragma unroll
    for (int r = 0; r < 4; r++) {
      prA[r] += fmaxf(accL[t][r] + bvA, 0.f) * wvA;
      prB[r] += fmaxf(accR[t][r] + bvB, 0.f) * wvB;
    }
  }
  #pragma unroll
  for (int o = 1; o < 16; o <<= 1)
    #pragma unroll
    for (int r = 0; r < 4; r++) {
      prA[r] += __shfl_xor(prA[r], o);
      prB[r] += __shfl_xor(prB[r], o);
    }
  if (ln16 == 0) {
    const float bb2a = b2a[0], bb2b = b2b[0];
    const int rbase = blockIdx.x * 64 + wave * 16 + quad * 4;
    #pragma unroll
    for (int r = 0; r < 4; r++) {
      int rr = rbase + r;
      if (rr < nrows) {
        out[(size_t)rr * 2 + 0] = prA[r] + bb2a;
        out[(size_t)rr * 2 + 1] = prB[r] + bb2b;
      }
    }
  }
}

// ---------- fused GAT layer -------------------------------------------------
// R7 structure: two rows per 64-lane wave, 2 edge-streams x 16 channel-lanes
// per row, 1-wave blocks, per-lane scalar index loads, depth-2 gather
// pipeline. R10: no NT hints (L3 retention, −12 us). R11: xl is fp16 (−62 us;
// halves gather payload). FROZEN.
template <int H>
__global__ __launch_bounds__(64) void gat_fused_kernel(
    const _Float16* __restrict__ xl, const float* __restrict__ xr,
    const int* __restrict__ csr_src, const int* __restrict__ row_end,
    const int* __restrict__ deg, const float* __restrict__ att,
    const float* __restrict__ res, const float* __restrict__ g,
    const float* __restrict__ b, float* __restrict__ y, int n,
    float resScale, int doRelu) {
  int l = threadIdx.x & 63;
  int rh = l >> 5;          // row-half within wave (0/1)
  int st = (l >> 4) & 1;    // edge-stream within row (0/1)
  int ln = l & 15;          // channel-lane within stream
  int row = blockIdx.x * 2 + rh;
  int rowC = row < n ? row : n - 1;  // clamp (stores guarded)
  int cb = ln * 32;   // byte offset of lane's 8-channel chunk (fp32 arrays)
  int cbh = ln * 16;  // byte offset in fp16 xl rows (256B/row)
  int end = row_end[rowC];
  int dg = deg[rowC] + 1;  // + self loop
  int start = end - dg;
  int cnt = (dg - st + 1) >> 1;  // edges for this stream (dg >= 1 always)

  const char* xrb = (const char*)xr + (size_t)rowC * 512 + cb;
  f4v xr0 = *(const f4v*)xrb;
  f4v xr1 = *(const f4v*)(xrb + 16);
  f4v av0 = *(const f4v*)((const char*)att + cb);
  f4v av1 = *(const f4v*)((const char*)att + cb + 16);

  float s = 0.f;
  float ac[8] = {0.f, 0.f, 0.f, 0.f, 0.f, 0.f, 0.f, 0.f};

  int idx = start + st;
  h8v pa = (h8v)0, pb = (h8v)0;  // depth-2 pipeline, fp16 payload
  if (cnt > 0)
    pa = *(const h8v*)((const char*)xl + (size_t)csr_src[idx] * 256 + cbh);
  if (cnt > 1)
    pb = *(const h8v*)((const char*)xl + (size_t)csr_src[idx + 2] * 256 + cbh);
  for (int i = 0; i < cnt; i++) {
    f8v xv = __builtin_convertvector(pa, f8v);
    pa = pb;
    if (i + 2 < cnt)
      pb = *(const h8v*)((const char*)xl + (size_t)csr_src[idx + 4] * 256 + cbh);
    idx += 2;
    float p0;
    {
      float t0 = xv[0] + xr0.x, t1 = xv[1] + xr0.y;
      float t2 = xv[2] + xr0.z, t3 = xv[3] + xr0.w;
      float t4 = xv[4] + xr1.x, t5 = xv[5] + xr1.y;
      float t6 = xv[6] + xr1.z, t7 = xv[7] + xr1.w;
      float v0 = fmaxf(t0, NEG_SLOPE * t0), v1 = fmaxf(t1, NEG_SLOPE * t1);
      float v2 = fmaxf(t2, NEG_SLOPE * t2), v3 = fmaxf(t3, NEG_SLOPE * t3);
      float v4 = fmaxf(t4, NEG_SLOPE * t4), v5 = fmaxf(t5, NEG_SLOPE * t5);
      float v6 = fmaxf(t6, NEG_SLOPE * t6), v7 = fmaxf(t7, NEG_SLOPE * t7);
      p0 = v0 * av0.x + v1 * av0.y + v2 * av0.z + v3 * av0.w +
           v4 * av1.x + v5 * av1.y + v6 * av1.z + v7 * av1.w;
    }
    if constexpr (H == 1) {  // logit over 128 ch = 16 lanes (one stream)
      #pragma unroll
      for (int o = 1; o < 16; o <<= 1) p0 += __shfl_xor(p0, o);
    } else {                 // H=4: head = 32 ch = 4 lanes
      p0 += __shfl_xor(p0, 1);
      p0 += __shfl_xor(p0, 2);
    }
    float e = __expf(p0);
    s += e;
    ac[0] += e * xv[0]; ac[1] += e * xv[1];
    ac[2] += e * xv[2]; ac[3] += e * xv[3];
    ac[4] += e * xv[4]; ac[5] += e * xv[5];
    ac[6] += e * xv[6]; ac[7] += e * xv[7];
  }
  // combine the two stream partials — xor 16 stays within this row's 32 lanes
  s += __shfl_xor(s, 16);
  #pragma unroll
  for (int j = 0; j < 8; j++) ac[j] += __shfl_xor(ac[j], 16);

  float inv = 1.f / s;
  float ov[8];
  #pragma unroll
  for (int j = 0; j < 8; j++) ov[j] = ac[j] * inv;

  // LayerNorm over 128 (16 lanes of a stream cover all channels)
  float sum = 0.f, sq = 0.f;
  #pragma unroll
  for (int j = 0; j < 8; j++) { sum += ov[j]; sq += ov[j] * ov[j]; }
  #pragma unroll
  for (int o = 1; o < 16; o <<= 1) {
    sum += __shfl_xor(sum, o);
    sq += __shfl_xor(sq, o);
  }
  float mean = sum * (1.f / 128.f);
  float var = sq * (1.f / 128.f) - mean * mean;
  float rstd = rsqrtf(var + 1e-5f);

  f4v gv0 = *(const f4v*)((const char*)g + cb);
  f4v gv1 = *(const f4v*)((const char*)g + cb + 16);
  f4v bv0 = *(const f4v*)((const char*)b + cb);
  f4v bv1 = *(const f4v*)((const char*)b + cb + 16);
  float gg[8] = {gv0.x, gv0.y, gv0.z, gv0.w, gv1.x, gv1.y, gv1.z, gv1.w};
  float bb[8] = {bv0.x, bv0.y, bv0.z, bv0.w, bv1.x, bv1.y, bv1.z, bv1.w};
  float rv[8];
  #pragma unroll
  for (int j = 0; j < 8; j++) rv[j] = (ov[j] - mean) * rstd * gg[j] + bb[j];
  if (res) {
    const char* rb = (const char*)res + (size_t)rowC * 512 + cb;
    f4v r0 = *(const f4v*)rb;
    f4v r1 = *(const f4v*)(rb + 16);
    rv[0] += resScale * r0.x; rv[1] += resScale * r0.y;
    rv[2] += resScale * r0.z; rv[3] += resScale * r0.w;
    rv[4] += resScale * r1.x; rv[5] += resScale * r1.y;
    rv[6] += resScale * r1.z; rv[7] += resScale * r1.w;
  }
  if (doRelu) {
    #pragma unroll
    for (int j = 0; j < 8; j++) rv[j] = fmaxf(rv[j], 0.f);
  }
  if (st == 0 && row < n) {
    char* yb = (char*)y + (size_t)row * 512 + cb;
    f4v o0 = {rv[0], rv[1], rv[2], rv[3]};
    f4v o1 = {rv[4], rv[5], rv[6], rv[7]};
    *(f4v*)yb = o0;
    *(f4v*)(yb + 16) = o1;
  }
}

// ---------- launch ----------
extern "C" void kernel_launch(void* const* d_in, const int* in_sizes, int n_in,
                              void* d_out, int out_size, void* d_ws,
                              size_t ws_size, hipStream_t stream) {
  const float* x       = (const float*)d_in[0];
  const int*   ei      = (const int*)d_in[1];
  const float* ln_in_g = (const float*)d_in[2];
  const float* ln_in_b = (const float*)d_in[3];
  const float* w_l1    = (const float*)d_in[4];
  const float* w_r1    = (const float*)d_in[5];
  const float* att1    = (const float*)d_in[6];
  const float* ln1_g   = (const float*)d_in[7];
  const float* ln1_b   = (const float*)d_in[8];
  const float* w_l2    = (const float*)d_in[9];
  const float* w_r2    = (const float*)d_in[10];
  const float* att2    = (const float*)d_in[11];
  const float* ln2_g   = (const float*)d_in[12];
  const float* ln2_b   = (const float*)d_in[13];
  const float* w_l3    = (const float*)d_in[14];
  const float* w_r3    = (const float*)d_in[15];
  const float* att3    = (const float*)d_in[16];
  const float* ln3_g   = (const float*)d_in[17];
  const float* ln3_b   = (const float*)d_in[18];
  const float* rtt_w1  = (const float*)d_in[19];
  const float* rtt_b1  = (const float*)d_in[20];
  const float* rtt_w2  = (const float*)d_in[21];
  const float* rtt_b2  = (const float*)d_in[22];
  const float* ret_w1  = (const float*)d_in[23];
  const float* ret_b1  = (const float*)d_in[24];
  const float* ret_w2  = (const float*)d_in[25];
  const float* ret_b2  = (const float*)d_in[26];

  const int N = in_sizes[0] / 64;
  const int E = in_sizes[1] / 2;
  const int ET = E + N;
  const size_t NF = (size_t)N * 128;

  float* A = (float*)d_ws;            // node features h / residual (fp32)
  _Float16* B = (_Float16*)(A + NF);  // xl (fp16; region sized NF floats)
  float* C = (float*)(A + 2 * NF);    // xr (fp32)
  int* deg     = (int*)(C + NF);      // N (edge-only degree; +1 = self loop)
  int* rowcur  = deg + N;             // N (row_end after scatter)
  int* incl    = rowcur + N;          // N
  int* bsums   = incl + N;            // 1024
  int* csr_src = bsums + 1024;        // ET
  short* wf = (short*)(((uintptr_t)(csr_src + ET) + 63) & ~(uintptr_t)63);

  float* out = (float*)d_out;

  // segments: wl1, wr1, wl2, wr2, wl3, wr3, rtt_w1, ret_w1
  const int segsz[8] = {64 * 128, 64 * 128, 128 * 128, 128 * 128,
                        128 * 128, 128 * 128, 128 * 64, 128 * 64};
  PrepArgs pa;
  pa.w[0] = w_l1; pa.w[1] = w_r1; pa.w[2] = w_l2; pa.w[3] = w_r2;
  pa.w[4] = w_l3; pa.w[5] = w_r3; pa.w[6] = rtt_w1; pa.w[7] = ret_w1;
  pa.fout[0] = 128; pa.fout[1] = 128; pa.fout[2] = 128; pa.fout[3] = 128;
  pa.fout[4] = 128; pa.fout[5] = 128; pa.fout[6] = 64; pa.fout[7] = 64;
  int acc = 0;
  short* op = wf;
  for (int s = 0; s < 8; s++) {
    pa.cum[s] = acc;
    pa.o[s] = op;
    op += 2 * segsz[s];  // h + l planes (dual fp16)
    acc += segsz[s];
  }
  pa.cum[8] = acc;

  const int mmBlocks   = (N + 63) / 64;    // head kernel + 16-row GEMMs
  const int gatBlocks  = (N + 1) / 2;      // gat: 2 rows per 1-wave block
  const int NB = (N + 1023) / 1024;
  dim3 lrGrid(mmBlocks, 2);

  // ---- W fragment prep ----
  prep_w_kernel<<<(acc + 255) / 256, 256, 0, stream>>>(pa);

  // ---- CSR build (by dst) ----
  hipMemsetAsync(deg, 0, (size_t)N * sizeof(int), stream);
  degree_count_kernel<<<(E + 255) / 256, 256, 0, stream>>>(ei, E, deg);
  scan1_kernel<<<NB, 1024, 0, stream>>>(deg, N, incl, bsums);
  scan23_kernel<<<NB, 1024, 0, stream>>>(incl, deg, bsums, NB, N, rowcur);
  scatter_kernel<<<(ET + 255) / 256, 256, 0, stream>>>(ei, E, ET, rowcur, csr_src);

  // ---- layer 0: fused LN64 + GEMM 64->128 (y-split L/R), 4 heads, relu ----
  mfma_gemm_ln_kernel<<<lrGrid, 256, 0, stream>>>(
      x, ln_in_g, ln_in_b, pa.o[0], pa.o[1], B, C, N);
  gat_fused_kernel<4><<<gatBlocks, 64, 0, stream>>>(
      B, C, csr_src, rowcur, deg, att1, nullptr, ln1_g, ln1_b, A, N, 0.f, 1);

  // ---- layer 1: 128 -> 128 (y-split L/R), 4 heads, residual 0.1, relu ----
  mfma_gemm_lr_kernel<<<lrGrid, 256, 0, stream>>>(A, pa.o[2], pa.o[3], B, C, N);
  gat_fused_kernel<4><<<gatBlocks, 64, 0, stream>>>(
      B, C, csr_src, rowcur, deg, att2, A, ln2_g, ln2_b, A, N, 0.1f, 1);

  // ---- layer 2: 128 -> 128 (y-split L/R), 1 head, residual 0.1, no relu ----
  mfma_gemm_lr_kernel<<<lrGrid, 256, 0, stream>>>(A, pa.o[4], pa.o[5], B, C, N);
  gat_fused_kernel<1><<<gatBlocks, 64, 0, stream>>>(
      B, C, csr_src, rowcur, deg, att3, A, ln3_g, ln3_b, A, N, 0.1f, 0);

  // ---- prediction heads: both GEMMs + relu + final dots in one dispatch ----
  mfma_head_lr_kernel<<<mmBlocks, 256, 0, stream>>>(
      A, pa.o[6], rtt_b1, rtt_w2, rtt_b2, pa.o[7], ret_b1, ret_w2, ret_b2,
      out, N);
}

// Round 14
// 503.542 us; speedup vs baseline: 1.1445x; 1.0592x over previous
//
#include <hip/hip_runtime.h>
#include <hip/hip_bf16.h>
#include <cstdint>
#include <cstddef>

#define NEG_SLOPE 0.2f

typedef float f4v __attribute__((ext_vector_type(4)));
typedef float f8v __attribute__((ext_vector_type(8)));
typedef _Float16 h8v __attribute__((ext_vector_type(8)));
typedef float f32x4 __attribute__((ext_vector_type(4)));

// ---- GEMM numerics ----
// R13: dual-fp16 split (2^-22 residual), 3 MFMA terms — PASSED at 1.46e-3.
// R14: A/xl/xr buffers are all fp16. The lr/head GEMM A-operand is then
// EXACT in fp16 -> split degenerates (al=0) -> 2 MFMA terms (ah*bh + ah*bl),
// zero conversion in the hot loop; GEMM error improves (only W residual).
// Quantizing A adds ~2.8e-4/GEMM downstream (same class as R11's xl-fp16,
// which measurably did not hurt). R6 LESSON: bf16 planes (2^-16) fail.
// R9 LESSON: y-split stays. R12: 16 rows/wave.
__device__ __forceinline__ void cvt2h(float v, _Float16& h, _Float16& l) {
  h = (_Float16)v;               // v_cvt_f16_f32, RNE in HW
  l = (_Float16)(v - (float)h);  // exact subtract, then RNE
}

// ---------- CSR build ----------

__global__ __launch_bounds__(256) void degree_count_kernel(
    const int* __restrict__ ei, int E, int* __restrict__ deg) {
  int e = blockIdx.x * 256 + threadIdx.x;
  if (e < E) atomicAdd(&deg[ei[E + e]], 1);
}

__global__ __launch_bounds__(1024) void scan1_kernel(
    const int* __restrict__ deg, int n, int* __restrict__ incl,
    int* __restrict__ blocksums) {
  __shared__ int sm[1024];
  int t = threadIdx.x;
  int i = blockIdx.x * 1024 + t;
  sm[t] = (i < n) ? (deg[i] + 1) : 0;  // +1: self loop
  __syncthreads();
  #pragma unroll
  for (int o = 1; o < 1024; o <<= 1) {
    int a = (t >= o) ? sm[t - o] : 0;
    __syncthreads();
    sm[t] += a;
    __syncthreads();
  }
  if (i < n) incl[i] = sm[t];
  if (t == 1023) blocksums[blockIdx.x] = sm[t];
}

__global__ __launch_bounds__(1024) void scan23_kernel(
    const int* __restrict__ incl, const int* __restrict__ deg,
    const int* __restrict__ bs, int nb, int n, int* __restrict__ rowcur) {
  int i = blockIdx.x * 1024 + threadIdx.x;
  if (i >= n) return;
  int off = 0;
  for (int j = 0; j < (int)blockIdx.x; j++) off += bs[j];  // nb<=98, L2-hot
  rowcur[i] = incl[i] - (deg[i] + 1) + off;
}

__global__ __launch_bounds__(256) void scatter_kernel(
    const int* __restrict__ ei, int E, int ET, int* __restrict__ rowcur,
    int* __restrict__ csr_src) {
  int e = blockIdx.x * 256 + threadIdx.x;
  if (e >= ET) return;
  int s, d;
  if (e < E) { s = ei[e]; d = ei[E + e]; }
  else       { s = e - E; d = s; }
  int pos = atomicAdd(&rowcur[d], 1);
  csr_src[pos] = s;
}

// ---------- W -> MFMA B-fragment layout (dual fp16 planes) ----------
struct PrepArgs {
  const float* w[8];
  short* o[8];
  int fout[8];
  int cum[9];
};

__global__ __launch_bounds__(256) void prep_w_kernel(PrepArgs pa) {
  int i = blockIdx.x * 256 + threadIdx.x;
  if (i >= pa.cum[8]) return;
  int s = 0;
  while (i >= pa.cum[s + 1]) s++;
  int li = i - pa.cum[s];
  int FOUT = pa.fout[s];
  int NT = FOUT >> 4;
  int sz = pa.cum[s + 1] - pa.cum[s];
  int c = li / (NT * 512);
  int r1 = li % (NT * 512);
  int t = r1 >> 9;
  int e = r1 & 511;
  int lane = e >> 3, j = e & 7;
  int k = c * 32 + (lane >> 4) * 8 + j;
  int n = t * 16 + (lane & 15);
  float v = pa.w[s][k * FOUT + n];
  _Float16 h, l;
  cvt2h(v, h, l);
  pa.o[s][li] = __builtin_bit_cast(short, h);
  pa.o[s][li + sz] = __builtin_bit_cast(short, l);
}

// 3-term dual-fp16 MFMA (fp32 A-side, layer 0)
#define MFMA3H(ah, al, bh, bl, acc)                                          \
  acc = __builtin_amdgcn_mfma_f32_16x16x32_f16(ah, bh, acc, 0, 0, 0);       \
  acc = __builtin_amdgcn_mfma_f32_16x16x32_f16(ah, bl, acc, 0, 0, 0);       \
  acc = __builtin_amdgcn_mfma_f32_16x16x32_f16(al, bh, acc, 0, 0, 0);

// 2-term MFMA (A exactly fp16, layers 1-2 + head)
#define MFMA2H(ah, bh, bl, acc)                                              \
  acc = __builtin_amdgcn_mfma_f32_16x16x32_f16(ah, bh, acc, 0, 0, 0);       \
  acc = __builtin_amdgcn_mfma_f32_16x16x32_f16(ah, bl, acc, 0, 0, 0);

// ---------- layer-0 GEMM: fused LN64, 16 rows/wave, y-split L/R ------------
// fp32 input -> 3-term split; BOTH outputs fp16 (R14).
__global__ __launch_bounds__(256, 4) void mfma_gemm_ln_kernel(
    const float* __restrict__ X, const float* __restrict__ lng,
    const float* __restrict__ lnb, const short* __restrict__ WfL,
    const short* __restrict__ WfR, _Float16* __restrict__ YL,
    _Float16* __restrict__ YR, int nrows) {
  constexpr int NT = 8, TOT = 2 * NT * 512;
  const short* Wf = blockIdx.y ? WfR : WfL;
  _Float16* Y = blockIdx.y ? YR : YL;
  const int wave = threadIdx.x >> 6, lane = threadIdx.x & 63;
  const int quad = lane >> 4, ln16 = lane & 15;
  const int rb = blockIdx.x * 64 + wave * 16;
  int r0 = rb + ln16;
  int rA0 = r0 < nrows ? r0 : nrows - 1;
  const float* xp0 = X + (size_t)rA0 * 64 + quad * 8;

  float av[16];
  *(float4*)&av[0]  = *(const float4*)(xp0);
  *(float4*)&av[4]  = *(const float4*)(xp0 + 4);
  *(float4*)&av[8]  = *(const float4*)(xp0 + 32);
  *(float4*)&av[12] = *(const float4*)(xp0 + 36);

  float s0 = 0.f, q0 = 0.f;
  #pragma unroll
  for (int j = 0; j < 16; j++) {
    s0 += av[j]; q0 += av[j] * av[j];
  }
  s0 += __shfl_xor(s0, 16); s0 += __shfl_xor(s0, 32);
  q0 += __shfl_xor(q0, 16); q0 += __shfl_xor(q0, 32);
  float mean0 = s0 * (1.f / 64.f);
  float rstd0 = rsqrtf(q0 * (1.f / 64.f) - mean0 * mean0 + 1e-5f);

  f32x4 acc[NT];
  #pragma unroll
  for (int t = 0; t < NT; t++) acc[t] = (f32x4){0.f, 0.f, 0.f, 0.f};

  #pragma unroll
  for (int c = 0; c < 2; c++) {
    float4 gv0 = *(const float4*)&lng[quad * 8 + c * 32];
    float4 gv1 = *(const float4*)&lng[quad * 8 + c * 32 + 4];
    float4 bv0 = *(const float4*)&lnb[quad * 8 + c * 32];
    float4 bv1 = *(const float4*)&lnb[quad * 8 + c * 32 + 4];
    float gg[8] = {gv0.x, gv0.y, gv0.z, gv0.w, gv1.x, gv1.y, gv1.z, gv1.w};
    float bb[8] = {bv0.x, bv0.y, bv0.z, bv0.w, bv1.x, bv1.y, bv1.z, bv1.w};
    h8v ah, al;
    #pragma unroll
    for (int j = 0; j < 8; j++) {
      float v0 = (av[c * 8 + j] - mean0) * rstd0 * gg[j] + bb[j];
      _Float16 h, l;
      cvt2h(v0, h, l); ah[j] = h; al[j] = l;
    }
    const short* wp = Wf + c * NT * 512 + lane * 8;
    #pragma unroll
    for (int t = 0; t < NT; t++) {
      h8v bh = *(const h8v*)(wp + t * 512);
      h8v bl = *(const h8v*)(wp + t * 512 + TOT);
      MFMA3H(ah, al, bh, bl, acc[t]);
    }
  }

  const int rbase = rb + quad * 4;
  #pragma unroll
  for (int t = 0; t < NT; t++)
    #pragma unroll
    for (int r = 0; r < 4; r++) {
      int ra = rbase + r;
      if (ra < nrows) Y[(size_t)ra * 128 + t * 16 + ln16] = (_Float16)acc[t][r];
    }
}

// ---------- generic MFMA GEMM: fp16 X, FIN=128, 16 rows/wave, y-split ------
// R14: X is fp16 (exact A-operand) -> one 16B load per c-iter, no cvt,
// 2 MFMA terms/tile.
__global__ __launch_bounds__(256, 4) void mfma_gemm_lr_kernel(
    const _Float16* __restrict__ X, const short* __restrict__ WfL,
    const short* __restrict__ WfR, _Float16* __restrict__ YL,
    _Float16* __restrict__ YR, int nrows) {
  constexpr int NC = 4, NT = 8, TOT = NC * NT * 512;
  const short* Wf = blockIdx.y ? WfR : WfL;
  _Float16* Y = blockIdx.y ? YR : YL;
  const int wave = threadIdx.x >> 6, lane = threadIdx.x & 63;
  const int quad = lane >> 4, ln16 = lane & 15;
  const int rb = blockIdx.x * 64 + wave * 16;
  int r0 = rb + ln16;
  int rA0 = r0 < nrows ? r0 : nrows - 1;
  const _Float16* xp0 = X + (size_t)rA0 * 128 + quad * 8;

  f32x4 acc[NT];
  #pragma unroll
  for (int t = 0; t < NT; t++) acc[t] = (f32x4){0.f, 0.f, 0.f, 0.f};

  #pragma unroll
  for (int c = 0; c < NC; c++) {
    h8v ah = *(const h8v*)(xp0 + c * 32);
    const short* wp = Wf + c * NT * 512 + lane * 8;
    #pragma unroll
    for (int t = 0; t < NT; t++) {
      h8v bh = *(const h8v*)(wp + t * 512);
      h8v bl = *(const h8v*)(wp + t * 512 + TOT);
      MFMA2H(ah, bh, bl, acc[t]);
    }
  }

  const int rbase = rb + quad * 4;
  #pragma unroll
  for (int t = 0; t < NT; t++)
    #pragma unroll
    for (int r = 0; r < 4; r++) {
      int ra = rbase + r;
      if (ra < nrows) Y[(size_t)ra * 128 + t * 16 + ln16] = (_Float16)acc[t][r];
    }
}

// ---------- head GEMMs fused with final dots: fp16 X -----------------------
__global__ __launch_bounds__(256, 2) void mfma_head_lr_kernel(
    const _Float16* __restrict__ X, const short* __restrict__ Wf1,
    const float* __restrict__ b1a, const float* __restrict__ w2a,
    const float* __restrict__ b2a, const short* __restrict__ Wf2,
    const float* __restrict__ b1b, const float* __restrict__ w2b,
    const float* __restrict__ b2b, float* __restrict__ out, int nrows) {
  constexpr int NC = 4, NT = 4, TOT = NC * NT * 512;
  const int wave = threadIdx.x >> 6, lane = threadIdx.x & 63;
  const int quad = lane >> 4, ln16 = lane & 15;
  int rowA = blockIdx.x * 64 + wave * 16 + ln16;
  int rA = rowA < nrows ? rowA : nrows - 1;
  const _Float16* xp = X + (size_t)rA * 128 + quad * 8;

  f32x4 accL[NT], accR[NT];
  #pragma unroll
  for (int t = 0; t < NT; t++) {
    accL[t] = (f32x4){0.f, 0.f, 0.f, 0.f};
    accR[t] = (f32x4){0.f, 0.f, 0.f, 0.f};
  }

  #pragma unroll
  for (int c = 0; c < NC; c++) {
    h8v ah = *(const h8v*)(xp + c * 32);
    const short* wpL = Wf1 + c * NT * 512 + lane * 8;
    const short* wpR = Wf2 + c * NT * 512 + lane * 8;
    #pragma unroll
    for (int t = 0; t < NT; t++) {
      h8v bh = *(const h8v*)(wpL + t * 512);
      h8v bl = *(const h8v*)(wpL + t * 512 + TOT);
      MFMA2H(ah, bh, bl, accL[t]);
      h8v ch = *(const h8v*)(wpR + t * 512);
      h8v cl = *(const h8v*)(wpR + t * 512 + TOT);
      MFMA2H(ah, ch, cl, accR[t]);
    }
  }

  float prA[4] = {0.f, 0.f, 0.f, 0.f};
  float prB[4] = {0.f, 0.f, 0.f, 0.f};
  #pragma unroll
  for (int t = 0; t < NT; t++) {
    float bvA = b1a[t * 16 + ln16], wvA = w2a[t * 16 + ln16];
    float bvB = b1b[t * 16 + ln16], wvB = w2b[t * 16 + ln16];
    #pragma unroll
    for (int r = 0; r < 4; r++) {
      prA[r] += fmaxf(accL[t][r] + bvA, 0.f) * wvA;
      prB[r] += fmaxf(accR[t][r] + bvB, 0.f) * wvB;
    }
  }
  #pragma unroll
  for (int o = 1; o < 16; o <<= 1)
    #pragma unroll
    for (int r = 0; r < 4; r++) {
      prA[r] += __shfl_xor(prA[r], o);
      prB[r] += __shfl_xor(prB[r], o);
    }
  if (ln16 == 0) {
    const float bb2a = b2a[0], bb2b = b2b[0];
    const int rbase = blockIdx.x * 64 + wave * 16 + quad * 4;
    #pragma unroll
    for (int r = 0; r < 4; r++) {
      int rr = rbase + r;
      if (rr < nrows) {
        out[(size_t)rr * 2 + 0] = prA[r] + bb2a;
        out[(size_t)rr * 2 + 1] = prB[r] + bb2b;
      }
    }
  }
}

// ---------- fused GAT layer -------------------------------------------------
// R7 structure (2 rows/wave, 2 streams x 16 lanes, 1-wave blocks, depth-2
// pipeline). R10: no NT hints. R11: xl fp16. R14: xr/res/y ALSO fp16 —
// per-row reads/writes halve; math stays fp32.
template <int H>
__global__ __launch_bounds__(64) void gat_fused_kernel(
    const _Float16* __restrict__ xl, const _Float16* __restrict__ xr,
    const int* __restrict__ csr_src, const int* __restrict__ row_end,
    const int* __restrict__ deg, const float* __restrict__ att,
    const _Float16* __restrict__ res, const float* __restrict__ g,
    const float* __restrict__ b, _Float16* __restrict__ y, int n,
    float resScale, int doRelu) {
  int l = threadIdx.x & 63;
  int rh = l >> 5;          // row-half within wave (0/1)
  int st = (l >> 4) & 1;    // edge-stream within row (0/1)
  int ln = l & 15;          // channel-lane within stream
  int row = blockIdx.x * 2 + rh;
  int rowC = row < n ? row : n - 1;  // clamp (stores guarded)
  int cb = ln * 32;   // byte offset in fp32 arrays (att/g/b)
  int cbh = ln * 16;  // byte offset in fp16 rows (256B/row)
  int end = row_end[rowC];
  int dg = deg[rowC] + 1;  // + self loop
  int start = end - dg;
  int cnt = (dg - st + 1) >> 1;  // edges for this stream (dg >= 1 always)

  h8v xrh = *(const h8v*)((const char*)xr + (size_t)rowC * 256 + cbh);
  f8v xrf = __builtin_convertvector(xrh, f8v);
  f4v av0 = *(const f4v*)((const char*)att + cb);
  f4v av1 = *(const f4v*)((const char*)att + cb + 16);

  float s = 0.f;
  float ac[8] = {0.f, 0.f, 0.f, 0.f, 0.f, 0.f, 0.f, 0.f};

  int idx = start + st;
  h8v pa = (h8v)0, pb = (h8v)0;  // depth-2 pipeline, fp16 payload
  if (cnt > 0)
    pa = *(const h8v*)((const char*)xl + (size_t)csr_src[idx] * 256 + cbh);
  if (cnt > 1)
    pb = *(const h8v*)((const char*)xl + (size_t)csr_src[idx + 2] * 256 + cbh);
  for (int i = 0; i < cnt; i++) {
    f8v xv = __builtin_convertvector(pa, f8v);
    pa = pb;
    if (i + 2 < cnt)
      pb = *(const h8v*)((const char*)xl + (size_t)csr_src[idx + 4] * 256 + cbh);
    idx += 2;
    float p0;
    {
      float t0 = xv[0] + xrf[0], t1 = xv[1] + xrf[1];
      float t2 = xv[2] + xrf[2], t3 = xv[3] + xrf[3];
      float t4 = xv[4] + xrf[4], t5 = xv[5] + xrf[5];
      float t6 = xv[6] + xrf[6], t7 = xv[7] + xrf[7];
      float v0 = fmaxf(t0, NEG_SLOPE * t0), v1 = fmaxf(t1, NEG_SLOPE * t1);
      float v2 = fmaxf(t2, NEG_SLOPE * t2), v3 = fmaxf(t3, NEG_SLOPE * t3);
      float v4 = fmaxf(t4, NEG_SLOPE * t4), v5 = fmaxf(t5, NEG_SLOPE * t5);
      float v6 = fmaxf(t6, NEG_SLOPE * t6), v7 = fmaxf(t7, NEG_SLOPE * t7);
      p0 = v0 * av0.x + v1 * av0.y + v2 * av0.z + v3 * av0.w +
           v4 * av1.x + v5 * av1.y + v6 * av1.z + v7 * av1.w;
    }
    if constexpr (H == 1) {  // logit over 128 ch = 16 lanes (one stream)
      #pragma unroll
      for (int o = 1; o < 16; o <<= 1) p0 += __shfl_xor(p0, o);
    } else {                 // H=4: head = 32 ch = 4 lanes
      p0 += __shfl_xor(p0, 1);
      p0 += __shfl_xor(p0, 2);
    }
    float e = __expf(p0);
    s += e;
    ac[0] += e * xv[0]; ac[1] += e * xv[1];
    ac[2] += e * xv[2]; ac[3] += e * xv[3];
    ac[4] += e * xv[4]; ac[5] += e * xv[5];
    ac[6] += e * xv[6]; ac[7] += e * xv[7];
  }
  // combine the two stream partials — xor 16 stays within this row's 32 lanes
  s += __shfl_xor(s, 16);
  #pragma unroll
  for (int j = 0; j < 8; j++) ac[j] += __shfl_xor(ac[j], 16);

  float inv = 1.f / s;
  float ov[8];
  #pragma unroll
  for (int j = 0; j < 8; j++) ov[j] = ac[j] * inv;

  // LayerNorm over 128 (16 lanes of a stream cover all channels)
  float sum = 0.f, sq = 0.f;
  #pragma unroll
  for (int j = 0; j < 8; j++) { sum += ov[j]; sq += ov[j] * ov[j]; }
  #pragma unroll
  for (int o = 1; o < 16; o <<= 1) {
    sum += __shfl_xor(sum, o);
    sq += __shfl_xor(sq, o);
  }
  float mean = sum * (1.f / 128.f);
  float var = sq * (1.f / 128.f) - mean * mean;
  float rstd = rsqrtf(var + 1e-5f);

  f4v gv0 = *(const f4v*)((const char*)g + cb);
  f4v gv1 = *(const f4v*)((const char*)g + cb + 16);
  f4v bv0 = *(const f4v*)((const char*)b + cb);
  f4v bv1 = *(const f4v*)((const char*)b + cb + 16);
  float gg[8] = {gv0.x, gv0.y, gv0.z, gv0.w, gv1.x, gv1.y, gv1.z, gv1.w};
  float bb[8] = {bv0.x, bv0.y, bv0.z, bv0.w, bv1.x, bv1.y, bv1.z, bv1.w};
  float rv[8];
  #pragma unroll
  for (int j = 0; j < 8; j++) rv[j] = (ov[j] - mean) * rstd * gg[j] + bb[j];
  if (res) {
    h8v rr = *(const h8v*)((const char*)res + (size_t)rowC * 256 + cbh);
    f8v rf = __builtin_convertvector(rr, f8v);
    #pragma unroll
    for (int j = 0; j < 8; j++) rv[j] += resScale * rf[j];
  }
  if (doRelu) {
    #pragma unroll
    for (int j = 0; j < 8; j++) rv[j] = fmaxf(rv[j], 0.f);
  }
  if (st == 0 && row < n) {
    f8v of;
    #pragma unroll
    for (int j = 0; j < 8; j++) of[j] = rv[j];
    h8v oh = __builtin_convertvector(of, h8v);
    *(h8v*)((char*)y + (size_t)row * 256 + cbh) = oh;
  }
}

// ---------- launch ----------
extern "C" void kernel_launch(void* const* d_in, const int* in_sizes, int n_in,
                              void* d_out, int out_size, void* d_ws,
                              size_t ws_size, hipStream_t stream) {
  const float* x       = (const float*)d_in[0];
  const int*   ei      = (const int*)d_in[1];
  const float* ln_in_g = (const float*)d_in[2];
  const float* ln_in_b = (const float*)d_in[3];
  const float* w_l1    = (const float*)d_in[4];
  const float* w_r1    = (const float*)d_in[5];
  const float* att1    = (const float*)d_in[6];
  const float* ln1_g   = (const float*)d_in[7];
  const float* ln1_b   = (const float*)d_in[8];
  const float* w_l2    = (const float*)d_in[9];
  const float* w_r2    = (const float*)d_in[10];
  const float* att2    = (const float*)d_in[11];
  const float* ln2_g   = (const float*)d_in[12];
  const float* ln2_b   = (const float*)d_in[13];
  const float* w_l3    = (const float*)d_in[14];
  const float* w_r3    = (const float*)d_in[15];
  const float* att3    = (const float*)d_in[16];
  const float* ln3_g   = (const float*)d_in[17];
  const float* ln3_b   = (const float*)d_in[18];
  const float* rtt_w1  = (const float*)d_in[19];
  const float* rtt_b1  = (const float*)d_in[20];
  const float* rtt_w2  = (const float*)d_in[21];
  const float* rtt_b2  = (const float*)d_in[22];
  const float* ret_w1  = (const float*)d_in[23];
  const float* ret_b1  = (const float*)d_in[24];
  const float* ret_w2  = (const float*)d_in[25];
  const float* ret_b2  = (const float*)d_in[26];

  const int N = in_sizes[0] / 64;
  const int E = in_sizes[1] / 2;
  const int ET = E + N;
  const size_t NF = (size_t)N * 128;

  _Float16* A = (_Float16*)d_ws;      // node features h / residual (fp16)
  _Float16* B = A + NF;               // xl (fp16)
  _Float16* C = B + NF;               // xr (fp16)
  int* deg     = (int*)(C + NF);      // N (edge-only degree; +1 = self loop)
  int* rowcur  = deg + N;             // N (row_end after scatter)
  int* incl    = rowcur + N;          // N
  int* bsums   = incl + N;            // 1024
  int* csr_src = bsums + 1024;        // ET
  short* wf = (short*)(((uintptr_t)(csr_src + ET) + 63) & ~(uintptr_t)63);

  float* out = (float*)d_out;

  // segments: wl1, wr1, wl2, wr2, wl3, wr3, rtt_w1, ret_w1
  const int segsz[8] = {64 * 128, 64 * 128, 128 * 128, 128 * 128,
                        128 * 128, 128 * 128, 128 * 64, 128 * 64};
  PrepArgs pa;
  pa.w[0] = w_l1; pa.w[1] = w_r1; pa.w[2] = w_l2; pa.w[3] = w_r2;
  pa.w[4] = w_l3; pa.w[5] = w_r3; pa.w[6] = rtt_w1; pa.w[7] = ret_w1;
  pa.fout[0] = 128; pa.fout[1] = 128; pa.fout[2] = 128; pa.fout[3] = 128;
  pa.fout[4] = 128; pa.fout[5] = 128; pa.fout[6] = 64; pa.fout[7] = 64;
  int acc = 0;
  short* op = wf;
  for (int s = 0; s < 8; s++) {
    pa.cum[s] = acc;
    pa.o[s] = op;
    op += 2 * segsz[s];  // h + l planes (dual fp16)
    acc += segsz[s];
  }
  pa.cum[8] = acc;

  const int mmBlocks   = (N + 63) / 64;    // head kernel + 16-row GEMMs
  const int gatBlocks  = (N + 1) / 2;      // gat: 2 rows per 1-wave block
  const int NB = (N + 1023) / 1024;
  dim3 lrGrid(mmBlocks, 2);

  // ---- W fragment prep ----
  prep_w_kernel<<<(acc + 255) / 256, 256, 0, stream>>>(pa);

  // ---- CSR build (by dst) ----
  hipMemsetAsync(deg, 0, (size_t)N * sizeof(int), stream);
  degree_count_kernel<<<(E + 255) / 256, 256, 0, stream>>>(ei, E, deg);
  scan1_kernel<<<NB, 1024, 0, stream>>>(deg, N, incl, bsums);
  scan23_kernel<<<NB, 1024, 0, stream>>>(incl, deg, bsums, NB, N, rowcur);
  scatter_kernel<<<(ET + 255) / 256, 256, 0, stream>>>(ei, E, ET, rowcur, csr_src);

  // ---- layer 0: fused LN64 + GEMM 64->128 (y-split L/R), 4 heads, relu ----
  mfma_gemm_ln_kernel<<<lrGrid, 256, 0, stream>>>(
      x, ln_in_g, ln_in_b, pa.o[0], pa.o[1], B, C, N);
  gat_fused_kernel<4><<<gatBlocks, 64, 0, stream>>>(
      B, C, csr_src, rowcur, deg, att1, nullptr, ln1_g, ln1_b, A, N, 0.f, 1);

  // ---- layer 1: 128 -> 128 (y-split L/R), 4 heads, residual 0.1, relu ----
  mfma_gemm_lr_kernel<<<lrGrid, 256, 0, stream>>>(A, pa.o[2], pa.o[3], B, C, N);
  gat_fused_kernel<4><<<gatBlocks, 64, 0, stream>>>(
      B, C, csr_src, rowcur, deg, att2, A, ln2_g, ln2_b, A, N, 0.1f, 1);

  // ---- layer 2: 128 -> 128 (y-split L/R), 1 head, residual 0.1, no relu ----
  mfma_gemm_lr_kernel<<<lrGrid, 256, 0, stream>>>(A, pa.o[4], pa.o[5], B, C, N);
  gat_fused_kernel<1><<<gatBlocks, 64, 0, stream>>>(
      B, C, csr_src, rowcur, deg, att3, A, ln3_g, ln3_b, A, N, 0.1f, 0);

  // ---- prediction heads: both GEMMs + relu + final dots in one dispatch ----
  mfma_head_lr_kernel<<<mmBlocks, 256, 0, stream>>>(
      A, pa.o[6], rtt_b1, rtt_w2, rtt_b2, pa.o[7], ret_b1, ret_w2, ret_b2,
      out, N);
}

// Round 15
// 451.674 us; speedup vs baseline: 1.2759x; 1.1148x over previous
//
#include <hip/hip_runtime.h>
#include <hip/hip_bf16.h>
#include <cstdint>
#include <cstddef>

#define NEG_SLOPE 0.2f

typedef float f4v __attribute__((ext_vector_type(4)));
typedef float f8v __attribute__((ext_vector_type(8)));
typedef _Float16 h8v __attribute__((ext_vector_type(8)));
typedef float f32x4 __attribute__((ext_vector_type(4)));

// ---- GEMM numerics ----
// R13: dual-fp16 W split (2^-22 residual). R14: fp16 A/xl/xr buffers ->
// lr/head GEMMs use exact-fp16 A, 2 MFMA terms. R6 LESSON: bf16 planes fail.
// R15: CSR scatter de-atomized via rank trick (deterministic layout) and
// fused with the ln GEMM dispatch; prep_w fused with degree pass.
__device__ __forceinline__ void cvt2h(float v, _Float16& h, _Float16& l) {
  h = (_Float16)v;               // v_cvt_f16_f32, RNE in HW
  l = (_Float16)(v - (float)h);  // exact subtract, then RNE
}

// ---------- W -> MFMA B-fragment layout (dual fp16 planes) ----------
struct PrepArgs {
  const float* w[8];
  short* o[8];
  int fout[8];
  int cum[9];
};

// ---------- fused: prep_w blocks + degree+rank blocks ----------------------
// deg[] zeroed by hipMemsetAsync beforehand. rank[e] = old deg (unique slot).
__global__ __launch_bounds__(256) void prep_degree_kernel(
    PrepArgs pa, int prepBlocks, const int* __restrict__ ei, int E,
    int* __restrict__ deg, int* __restrict__ rank) {
  if ((int)blockIdx.x < prepBlocks) {
    int i = blockIdx.x * 256 + threadIdx.x;
    if (i >= pa.cum[8]) return;
    int s = 0;
    while (i >= pa.cum[s + 1]) s++;
    int li = i - pa.cum[s];
    int FOUT = pa.fout[s];
    int NT = FOUT >> 4;
    int sz = pa.cum[s + 1] - pa.cum[s];
    int c = li / (NT * 512);
    int r1 = li % (NT * 512);
    int t = r1 >> 9;
    int e = r1 & 511;
    int lane = e >> 3, j = e & 7;
    int k = c * 32 + (lane >> 4) * 8 + j;
    int n = t * 16 + (lane & 15);
    float v = pa.w[s][k * FOUT + n];
    _Float16 h, l;
    cvt2h(v, h, l);
    pa.o[s][li] = __builtin_bit_cast(short, h);
    pa.o[s][li + sz] = __builtin_bit_cast(short, l);
  } else {
    int e = ((int)blockIdx.x - prepBlocks) * 256 + threadIdx.x;
    if (e < E) rank[e] = atomicAdd(&deg[ei[E + e]], 1);
  }
}

__global__ __launch_bounds__(1024) void scan1_kernel(
    const int* __restrict__ deg, int n, int* __restrict__ incl,
    int* __restrict__ blocksums) {
  __shared__ int sm[1024];
  int t = threadIdx.x;
  int i = blockIdx.x * 1024 + t;
  sm[t] = (i < n) ? (deg[i] + 1) : 0;  // +1: self loop
  __syncthreads();
  #pragma unroll
  for (int o = 1; o < 1024; o <<= 1) {
    int a = (t >= o) ? sm[t - o] : 0;
    __syncthreads();
    sm[t] += a;
    __syncthreads();
  }
  if (i < n) incl[i] = sm[t];
  if (t == 1023) blocksums[blockIdx.x] = sm[t];
}

// scan3 with scan2 folded in; writes exclusive row STARTS (read-only after).
__global__ __launch_bounds__(1024) void scan23_kernel(
    const int* __restrict__ incl, const int* __restrict__ deg,
    const int* __restrict__ bs, int nb, int n, int* __restrict__ rowstart) {
  int i = blockIdx.x * 1024 + threadIdx.x;
  if (i >= n) return;
  int off = 0;
  for (int j = 0; j < (int)blockIdx.x; j++) off += bs[j];  // nb<=98, L2-hot
  rowstart[i] = incl[i] - (deg[i] + 1) + off;
}

// 3-term dual-fp16 MFMA (fp32 A-side, layer 0)
#define MFMA3H(ah, al, bh, bl, acc)                                          \
  acc = __builtin_amdgcn_mfma_f32_16x16x32_f16(ah, bh, acc, 0, 0, 0);       \
  acc = __builtin_amdgcn_mfma_f32_16x16x32_f16(ah, bl, acc, 0, 0, 0);       \
  acc = __builtin_amdgcn_mfma_f32_16x16x32_f16(al, bh, acc, 0, 0, 0);

// 2-term MFMA (A exactly fp16, layers 1-2 + head)
#define MFMA2H(ah, bh, bl, acc)                                              \
  acc = __builtin_amdgcn_mfma_f32_16x16x32_f16(ah, bh, acc, 0, 0, 0);       \
  acc = __builtin_amdgcn_mfma_f32_16x16x32_f16(ah, bl, acc, 0, 0, 0);

// ---------- fused: layer-0 LN64 GEMM blocks + atomic-free scatter blocks ---
// ln part: 16 rows/wave, y-split L/R (flattened: side = b >= lnB).
// scatter part: csr_src[rowstart[d] + rank[e]] = s (self-loop slot deg[d]).
// Scatter blocks (latency-bound, 0.4% VALU measured R14) fill the GEMM's
// stall slots — saves the previously-serialized ~25 us ln GEMM time.
__global__ __launch_bounds__(256, 4) void ln_scatter_kernel(
    const float* __restrict__ X, const float* __restrict__ lng,
    const float* __restrict__ lnb, const short* __restrict__ WfL,
    const short* __restrict__ WfR, _Float16* __restrict__ YL,
    _Float16* __restrict__ YR, int nrows, int lnB,
    const int* __restrict__ ei, int E, int ET,
    const int* __restrict__ rowstart, const int* __restrict__ rank,
    const int* __restrict__ deg, int* __restrict__ csr_src) {
  int b = blockIdx.x;
  if (b >= 2 * lnB) {
    int e = (b - 2 * lnB) * 256 + threadIdx.x;
    if (e < ET) {
      int s, d, r;
      if (e < E) { s = ei[e]; d = ei[E + e]; r = rank[e]; }
      else       { s = e - E; d = s; r = deg[d]; }
      csr_src[rowstart[d] + r] = s;
    }
    return;
  }
  constexpr int NT = 8, TOT = 2 * NT * 512;
  const int side = (b >= lnB);
  const int bx = b - side * lnB;
  const short* Wf = side ? WfR : WfL;
  _Float16* Y = side ? YR : YL;
  const int wave = threadIdx.x >> 6, lane = threadIdx.x & 63;
  const int quad = lane >> 4, ln16 = lane & 15;
  const int rb = bx * 64 + wave * 16;
  int r0 = rb + ln16;
  int rA0 = r0 < nrows ? r0 : nrows - 1;
  const float* xp0 = X + (size_t)rA0 * 64 + quad * 8;

  float av[16];
  *(float4*)&av[0]  = *(const float4*)(xp0);
  *(float4*)&av[4]  = *(const float4*)(xp0 + 4);
  *(float4*)&av[8]  = *(const float4*)(xp0 + 32);
  *(float4*)&av[12] = *(const float4*)(xp0 + 36);

  float s0 = 0.f, q0 = 0.f;
  #pragma unroll
  for (int j = 0; j < 16; j++) {
    s0 += av[j]; q0 += av[j] * av[j];
  }
  s0 += __shfl_xor(s0, 16); s0 += __shfl_xor(s0, 32);
  q0 += __shfl_xor(q0, 16); q0 += __shfl_xor(q0, 32);
  float mean0 = s0 * (1.f / 64.f);
  float rstd0 = rsqrtf(q0 * (1.f / 64.f) - mean0 * mean0 + 1e-5f);

  f32x4 acc[NT];
  #pragma unroll
  for (int t = 0; t < NT; t++) acc[t] = (f32x4){0.f, 0.f, 0.f, 0.f};

  #pragma unroll
  for (int c = 0; c < 2; c++) {
    float4 gv0 = *(const float4*)&lng[quad * 8 + c * 32];
    float4 gv1 = *(const float4*)&lng[quad * 8 + c * 32 + 4];
    float4 bv0 = *(const float4*)&lnb[quad * 8 + c * 32];
    float4 bv1 = *(const float4*)&lnb[quad * 8 + c * 32 + 4];
    float gg[8] = {gv0.x, gv0.y, gv0.z, gv0.w, gv1.x, gv1.y, gv1.z, gv1.w};
    float bb[8] = {bv0.x, bv0.y, bv0.z, bv0.w, bv1.x, bv1.y, bv1.z, bv1.w};
    h8v ah, al;
    #pragma unroll
    for (int j = 0; j < 8; j++) {
      float v0 = (av[c * 8 + j] - mean0) * rstd0 * gg[j] + bb[j];
      _Float16 h, l;
      cvt2h(v0, h, l); ah[j] = h; al[j] = l;
    }
    const short* wp = Wf + c * NT * 512 + lane * 8;
    #pragma unroll
    for (int t = 0; t < NT; t++) {
      h8v bh = *(const h8v*)(wp + t * 512);
      h8v bl = *(const h8v*)(wp + t * 512 + TOT);
      MFMA3H(ah, al, bh, bl, acc[t]);
    }
  }

  const int rbase = rb + quad * 4;
  #pragma unroll
  for (int t = 0; t < NT; t++)
    #pragma unroll
    for (int r = 0; r < 4; r++) {
      int ra = rbase + r;
      if (ra < nrows) Y[(size_t)ra * 128 + t * 16 + ln16] = (_Float16)acc[t][r];
    }
}

// ---------- generic MFMA GEMM: fp16 X, FIN=128, 16 rows/wave, y-split ------
__global__ __launch_bounds__(256, 4) void mfma_gemm_lr_kernel(
    const _Float16* __restrict__ X, const short* __restrict__ WfL,
    const short* __restrict__ WfR, _Float16* __restrict__ YL,
    _Float16* __restrict__ YR, int nrows) {
  constexpr int NC = 4, NT = 8, TOT = NC * NT * 512;
  const short* Wf = blockIdx.y ? WfR : WfL;
  _Float16* Y = blockIdx.y ? YR : YL;
  const int wave = threadIdx.x >> 6, lane = threadIdx.x & 63;
  const int quad = lane >> 4, ln16 = lane & 15;
  const int rb = blockIdx.x * 64 + wave * 16;
  int r0 = rb + ln16;
  int rA0 = r0 < nrows ? r0 : nrows - 1;
  const _Float16* xp0 = X + (size_t)rA0 * 128 + quad * 8;

  f32x4 acc[NT];
  #pragma unroll
  for (int t = 0; t < NT; t++) acc[t] = (f32x4){0.f, 0.f, 0.f, 0.f};

  #pragma unroll
  for (int c = 0; c < NC; c++) {
    h8v ah = *(const h8v*)(xp0 + c * 32);
    const short* wp = Wf + c * NT * 512 + lane * 8;
    #pragma unroll
    for (int t = 0; t < NT; t++) {
      h8v bh = *(const h8v*)(wp + t * 512);
      h8v bl = *(const h8v*)(wp + t * 512 + TOT);
      MFMA2H(ah, bh, bl, acc[t]);
    }
  }

  const int rbase = rb + quad * 4;
  #pragma unroll
  for (int t = 0; t < NT; t++)
    #pragma unroll
    for (int r = 0; r < 4; r++) {
      int ra = rbase + r;
      if (ra < nrows) Y[(size_t)ra * 128 + t * 16 + ln16] = (_Float16)acc[t][r];
    }
}

// ---------- head GEMMs fused with final dots: fp16 X -----------------------
__global__ __launch_bounds__(256, 2) void mfma_head_lr_kernel(
    const _Float16* __restrict__ X, const short* __restrict__ Wf1,
    const float* __restrict__ b1a, const float* __restrict__ w2a,
    const float* __restrict__ b2a, const short* __restrict__ Wf2,
    const float* __restrict__ b1b, const float* __restrict__ w2b,
    const float* __restrict__ b2b, float* __restrict__ out, int nrows) {
  constexpr int NC = 4, NT = 4, TOT = NC * NT * 512;
  const int wave = threadIdx.x >> 6, lane = threadIdx.x & 63;
  const int quad = lane >> 4, ln16 = lane & 15;
  int rowA = blockIdx.x * 64 + wave * 16 + ln16;
  int rA = rowA < nrows ? rowA : nrows - 1;
  const _Float16* xp = X + (size_t)rA * 128 + quad * 8;

  f32x4 accL[NT], accR[NT];
  #pragma unroll
  for (int t = 0; t < NT; t++) {
    accL[t] = (f32x4){0.f, 0.f, 0.f, 0.f};
    accR[t] = (f32x4){0.f, 0.f, 0.f, 0.f};
  }

  #pragma unroll
  for (int c = 0; c < NC; c++) {
    h8v ah = *(const h8v*)(xp + c * 32);
    const short* wpL = Wf1 + c * NT * 512 + lane * 8;
    const short* wpR = Wf2 + c * NT * 512 + lane * 8;
    #pragma unroll
    for (int t = 0; t < NT; t++) {
      h8v bh = *(const h8v*)(wpL + t * 512);
      h8v bl = *(const h8v*)(wpL + t * 512 + TOT);
      MFMA2H(ah, bh, bl, accL[t]);
      h8v ch = *(const h8v*)(wpR + t * 512);
      h8v cl = *(const h8v*)(wpR + t * 512 + TOT);
      MFMA2H(ah, ch, cl, accR[t]);
    }
  }

  float prA[4] = {0.f, 0.f, 0.f, 0.f};
  float prB[4] = {0.f, 0.f, 0.f, 0.f};
  #pragma unroll
  for (int t = 0; t < NT; t++) {
    float bvA = b1a[t * 16 + ln16], wvA = w2a[t * 16 + ln16];
    float bvB = b1b[t * 16 + ln16], wvB = w2b[t * 16 + ln16];
    #pragma unroll
    for (int r = 0; r < 4; r++) {
      prA[r] += fmaxf(accL[t][r] + bvA, 0.f) * wvA;
      prB[r] += fmaxf(accR[t][r] + bvB, 0.f) * wvB;
    }
  }
  #pragma unroll
  for (int o = 1; o < 16; o <<= 1)
    #pragma unroll
    for (int r = 0; r < 4; r++) {
      prA[r] += __shfl_xor(prA[r], o);
      prB[r] += __shfl_xor(prB[r], o);
    }
  if (ln16 == 0) {
    const float bb2a = b2a[0], bb2b = b2b[0];
    const int rbase = blockIdx.x * 64 + wave * 16 + quad * 4;
    #pragma unroll
    for (int r = 0; r < 4; r++) {
      int rr = rbase + r;
      if (rr < nrows) {
        out[(size_t)rr * 2 + 0] = prA[r] + bb2a;
        out[(size_t)rr * 2 + 1] = prB[r] + bb2b;
      }
    }
  }
}

// ---------- fused GAT layer -------------------------------------------------
// R7 structure (2 rows/wave, 2 streams x 16 lanes, 1-wave blocks, depth-2
// pipeline). R10: no NT hints. R11/R14: all fp16 buffers. R15: takes
// row START (CSR start, read-only) instead of post-scatter row end.
template <int H>
__global__ __launch_bounds__(64) void gat_fused_kernel(
    const _Float16* __restrict__ xl, const _Float16* __restrict__ xr,
    const int* __restrict__ csr_src, const int* __restrict__ row_start,
    const int* __restrict__ deg, const float* __restrict__ att,
    const _Float16* __restrict__ res, const float* __restrict__ g,
    const float* __restrict__ b, _Float16* __restrict__ y, int n,
    float resScale, int doRelu) {
  int l = threadIdx.x & 63;
  int rh = l >> 5;          // row-half within wave (0/1)
  int st = (l >> 4) & 1;    // edge-stream within row (0/1)
  int ln = l & 15;          // channel-lane within stream
  int row = blockIdx.x * 2 + rh;
  int rowC = row < n ? row : n - 1;  // clamp (stores guarded)
  int cb = ln * 32;   // byte offset in fp32 arrays (att/g/b)
  int cbh = ln * 16;  // byte offset in fp16 rows (256B/row)
  int start = row_start[rowC];
  int dg = deg[rowC] + 1;  // + self loop
  int cnt = (dg - st + 1) >> 1;  // edges for this stream (dg >= 1 always)

  h8v xrh = *(const h8v*)((const char*)xr + (size_t)rowC * 256 + cbh);
  f8v xrf = __builtin_convertvector(xrh, f8v);
  f4v av0 = *(const f4v*)((const char*)att + cb);
  f4v av1 = *(const f4v*)((const char*)att + cb + 16);

  float s = 0.f;
  float ac[8] = {0.f, 0.f, 0.f, 0.f, 0.f, 0.f, 0.f, 0.f};

  int idx = start + st;
  h8v pa = (h8v)0, pb = (h8v)0;  // depth-2 pipeline, fp16 payload
  if (cnt > 0)
    pa = *(const h8v*)((const char*)xl + (size_t)csr_src[idx] * 256 + cbh);
  if (cnt > 1)
    pb = *(const h8v*)((const char*)xl + (size_t)csr_src[idx + 2] * 256 + cbh);
  for (int i = 0; i < cnt; i++) {
    f8v xv = __builtin_convertvector(pa, f8v);
    pa = pb;
    if (i + 2 < cnt)
      pb = *(const h8v*)((const char*)xl + (size_t)csr_src[idx + 4] * 256 + cbh);
    idx += 2;
    float p0;
    {
      float t0 = xv[0] + xrf[0], t1 = xv[1] + xrf[1];
      float t2 = xv[2] + xrf[2], t3 = xv[3] + xrf[3];
      float t4 = xv[4] + xrf[4], t5 = xv[5] + xrf[5];
      float t6 = xv[6] + xrf[6], t7 = xv[7] + xrf[7];
      float v0 = fmaxf(t0, NEG_SLOPE * t0), v1 = fmaxf(t1, NEG_SLOPE * t1);
      float v2 = fmaxf(t2, NEG_SLOPE * t2), v3 = fmaxf(t3, NEG_SLOPE * t3);
      float v4 = fmaxf(t4, NEG_SLOPE * t4), v5 = fmaxf(t5, NEG_SLOPE * t5);
      float v6 = fmaxf(t6, NEG_SLOPE * t6), v7 = fmaxf(t7, NEG_SLOPE * t7);
      p0 = v0 * av0.x + v1 * av0.y + v2 * av0.z + v3 * av0.w +
           v4 * av1.x + v5 * av1.y + v6 * av1.z + v7 * av1.w;
    }
    if constexpr (H == 1) {  // logit over 128 ch = 16 lanes (one stream)
      #pragma unroll
      for (int o = 1; o < 16; o <<= 1) p0 += __shfl_xor(p0, o);
    } else {                 // H=4: head = 32 ch = 4 lanes
      p0 += __shfl_xor(p0, 1);
      p0 += __shfl_xor(p0, 2);
    }
    float e = __expf(p0);
    s += e;
    ac[0] += e * xv[0]; ac[1] += e * xv[1];
    ac[2] += e * xv[2]; ac[3] += e * xv[3];
    ac[4] += e * xv[4]; ac[5] += e * xv[5];
    ac[6] += e * xv[6]; ac[7] += e * xv[7];
  }
  // combine the two stream partials — xor 16 stays within this row's 32 lanes
  s += __shfl_xor(s, 16);
  #pragma unroll
  for (int j = 0; j < 8; j++) ac[j] += __shfl_xor(ac[j], 16);

  float inv = 1.f / s;
  float ov[8];
  #pragma unroll
  for (int j = 0; j < 8; j++) ov[j] = ac[j] * inv;

  // LayerNorm over 128 (16 lanes of a stream cover all channels)
  float sum = 0.f, sq = 0.f;
  #pragma unroll
  for (int j = 0; j < 8; j++) { sum += ov[j]; sq += ov[j] * ov[j]; }
  #pragma unroll
  for (int o = 1; o < 16; o <<= 1) {
    sum += __shfl_xor(sum, o);
    sq += __shfl_xor(sq, o);
  }
  float mean = sum * (1.f / 128.f);
  float var = sq * (1.f / 128.f) - mean * mean;
  float rstd = rsqrtf(var + 1e-5f);

  f4v gv0 = *(const f4v*)((const char*)g + cb);
  f4v gv1 = *(const f4v*)((const char*)g + cb + 16);
  f4v bv0 = *(const f4v*)((const char*)b + cb);
  f4v bv1 = *(const f4v*)((const char*)b + cb + 16);
  float gg[8] = {gv0.x, gv0.y, gv0.z, gv0.w, gv1.x, gv1.y, gv1.z, gv1.w};
  float bb[8] = {bv0.x, bv0.y, bv0.z, bv0.w, bv1.x, bv1.y, bv1.z, bv1.w};
  float rv[8];
  #pragma unroll
  for (int j = 0; j < 8; j++) rv[j] = (ov[j] - mean) * rstd * gg[j] + bb[j];
  if (res) {
    h8v rr = *(const h8v*)((const char*)res + (size_t)rowC * 256 + cbh);
    f8v rf = __builtin_convertvector(rr, f8v);
    #pragma unroll
    for (int j = 0; j < 8; j++) rv[j] += resScale * rf[j];
  }
  if (doRelu) {
    #pragma unroll
    for (int j = 0; j < 8; j++) rv[j] = fmaxf(rv[j], 0.f);
  }
  if (st == 0 && row < n) {
    f8v of;
    #pragma unroll
    for (int j = 0; j < 8; j++) of[j] = rv[j];
    h8v oh = __builtin_convertvector(of, h8v);
    *(h8v*)((char*)y + (size_t)row * 256 + cbh) = oh;
  }
}

// ---------- launch ----------
extern "C" void kernel_launch(void* const* d_in, const int* in_sizes, int n_in,
                              void* d_out, int out_size, void* d_ws,
                              size_t ws_size, hipStream_t stream) {
  const float* x       = (const float*)d_in[0];
  const int*   ei      = (const int*)d_in[1];
  const float* ln_in_g = (const float*)d_in[2];
  const float* ln_in_b = (const float*)d_in[3];
  const float* w_l1    = (const float*)d_in[4];
  const float* w_r1    = (const float*)d_in[5];
  const float* att1    = (const float*)d_in[6];
  const float* ln1_g   = (const float*)d_in[7];
  const float* ln1_b   = (const float*)d_in[8];
  const float* w_l2    = (const float*)d_in[9];
  const float* w_r2    = (const float*)d_in[10];
  const float* att2    = (const float*)d_in[11];
  const float* ln2_g   = (const float*)d_in[12];
  const float* ln2_b   = (const float*)d_in[13];
  const float* w_l3    = (const float*)d_in[14];
  const float* w_r3    = (const float*)d_in[15];
  const float* att3    = (const float*)d_in[16];
  const float* ln3_g   = (const float*)d_in[17];
  const float* ln3_b   = (const float*)d_in[18];
  const float* rtt_w1  = (const float*)d_in[19];
  const float* rtt_b1  = (const float*)d_in[20];
  const float* rtt_w2  = (const float*)d_in[21];
  const float* rtt_b2  = (const float*)d_in[22];
  const float* ret_w1  = (const float*)d_in[23];
  const float* ret_b1  = (const float*)d_in[24];
  const float* ret_w2  = (const float*)d_in[25];
  const float* ret_b2  = (const float*)d_in[26];

  const int N = in_sizes[0] / 64;
  const int E = in_sizes[1] / 2;
  const int ET = E + N;
  const size_t NF = (size_t)N * 128;

  _Float16* A = (_Float16*)d_ws;      // node features h / residual (fp16)
  _Float16* B = A + NF;               // xl (fp16)
  _Float16* C = B + NF;               // xr (fp16)
  int* deg      = (int*)(C + NF);     // N (edge-only degree)
  int* rowstart = deg + N;            // N (exclusive row starts, read-only)
  int* incl     = rowstart + N;       // N
  int* bsums    = incl + N;           // 1024
  int* csr_src  = bsums + 1024;       // ET
  int* rank     = csr_src + ET;       // E (per-edge slot within its row)
  short* wf = (short*)(((uintptr_t)(rank + E) + 63) & ~(uintptr_t)63);

  float* out = (float*)d_out;

  // segments: wl1, wr1, wl2, wr2, wl3, wr3, rtt_w1, ret_w1
  const int segsz[8] = {64 * 128, 64 * 128, 128 * 128, 128 * 128,
                        128 * 128, 128 * 128, 128 * 64, 128 * 64};
  PrepArgs pa;
  pa.w[0] = w_l1; pa.w[1] = w_r1; pa.w[2] = w_l2; pa.w[3] = w_r2;
  pa.w[4] = w_l3; pa.w[5] = w_r3; pa.w[6] = rtt_w1; pa.w[7] = ret_w1;
  pa.fout[0] = 128; pa.fout[1] = 128; pa.fout[2] = 128; pa.fout[3] = 128;
  pa.fout[4] = 128; pa.fout[5] = 128; pa.fout[6] = 64; pa.fout[7] = 64;
  int acc = 0;
  short* op = wf;
  for (int s = 0; s < 8; s++) {
    pa.cum[s] = acc;
    pa.o[s] = op;
    op += 2 * segsz[s];  // h + l planes (dual fp16)
    acc += segsz[s];
  }
  pa.cum[8] = acc;

  const int mmBlocks   = (N + 63) / 64;    // head kernel + 16-row GEMMs
  const int gatBlocks  = (N + 1) / 2;      // gat: 2 rows per 1-wave block
  const int NB = (N + 1023) / 1024;
  const int prepBlocks = (acc + 255) / 256;
  const int degBlocks  = (E + 255) / 256;
  const int scatBlocks = (ET + 255) / 256;
  dim3 lrGrid(mmBlocks, 2);

  // ---- CSR degree (+rank) fused with W fragment prep ----
  hipMemsetAsync(deg, 0, (size_t)N * sizeof(int), stream);
  prep_degree_kernel<<<prepBlocks + degBlocks, 256, 0, stream>>>(
      pa, prepBlocks, ei, E, deg, rank);
  scan1_kernel<<<NB, 1024, 0, stream>>>(deg, N, incl, bsums);
  scan23_kernel<<<NB, 1024, 0, stream>>>(incl, deg, bsums, NB, N, rowstart);

  // ---- layer 0 GEMM fused with atomic-free scatter ----
  ln_scatter_kernel<<<2 * mmBlocks + scatBlocks, 256, 0, stream>>>(
      x, ln_in_g, ln_in_b, pa.o[0], pa.o[1], B, C, N, mmBlocks,
      ei, E, ET, rowstart, rank, deg, csr_src);
  gat_fused_kernel<4><<<gatBlocks, 64, 0, stream>>>(
      B, C, csr_src, rowstart, deg, att1, nullptr, ln1_g, ln1_b, A, N, 0.f, 1);

  // ---- layer 1: 128 -> 128 (y-split L/R), 4 heads, residual 0.1, relu ----
  mfma_gemm_lr_kernel<<<lrGrid, 256, 0, stream>>>(A, pa.o[2], pa.o[3], B, C, N);
  gat_fused_kernel<4><<<gatBlocks, 64, 0, stream>>>(
      B, C, csr_src, rowstart, deg, att2, A, ln2_g, ln2_b, A, N, 0.1f, 1);

  // ---- layer 2: 128 -> 128 (y-split L/R), 1 head, residual 0.1, no relu ----
  mfma_gemm_lr_kernel<<<lrGrid, 256, 0, stream>>>(A, pa.o[4], pa.o[5], B, C, N);
  gat_fused_kernel<1><<<gatBlocks, 64, 0, stream>>>(
      B, C, csr_src, rowstart, deg, att3, A, ln3_g, ln3_b, A, N, 0.1f, 0);

  // ---- prediction heads: both GEMMs + relu + final dots in one dispatch ----
  mfma_head_lr_kernel<<<mmBlocks, 256, 0, stream>>>(
      A, pa.o[6], rtt_b1, rtt_w2, rtt_b2, pa.o[7], ret_b1, ret_w2, ret_b2,
      out, N);
}